// Round 1
// baseline (3756.383 us; speedup 1.0000x reference)
//
#include <hip/hip_runtime.h>
#include <cstddef>

#define EPS_C   1e-5f
#define DELTA_C 0.05f

// ---------- H = relu(LN(A @ W1 + b1)) ; A:(64,K), W1:(K,256), H:(64,256) ----------
__global__ __launch_bounds__(256) void head_mlp(
    const float* __restrict__ A, const float* __restrict__ W1,
    const float* __restrict__ b1, const float* __restrict__ g,
    const float* __restrict__ bb, float* __restrict__ H, int K)
{
  int row = blockIdx.x, j = threadIdx.x;
  float acc = b1[j];
  for (int c = 0; c < K; ++c) acc += A[row * K + c] * W1[c * 256 + j];
  __shared__ float rs[256], rs2[256];
  rs[j] = acc; rs2[j] = acc * acc;
  __syncthreads();
  for (int st = 128; st > 0; st >>= 1) {
    if (j < st) { rs[j] += rs[j + st]; rs2[j] += rs2[j + st]; }
    __syncthreads();
  }
  float mu  = rs[0] * (1.f / 256.f);
  float var = rs2[0] * (1.f / 256.f) - mu * mu;
  float y = (acc - mu) * rsqrtf(var + EPS_C) * g[j] + bb[j];
  H[row * 256 + j] = fmaxf(y, 0.f);
}

// ---------- emb -> Vmat: Vmat[f][n][l] = (Hs@sW2 + sb2 + Ht@tW2 + tb2)[l][n*64+f] ----------
__global__ __launch_bounds__(256) void emb_to_v(
    const float* __restrict__ Hs, const float* __restrict__ Ht,
    const float* __restrict__ sW2, const float* __restrict__ sb2,
    const float* __restrict__ tW2, const float* __restrict__ tb2,
    float* __restrict__ Vmat)
{
  int n = blockIdx.x;
  int tid = threadIdx.x;
  int f = tid & 63, lg = tid >> 6;
  __shared__ float wbuf[64][65];   // W2 chunk [cc][f]
  __shared__ float hbuf[64][65];   // H  chunk [l][cc]
  float acc[16];
#pragma unroll
  for (int i = 0; i < 16; ++i) acc[i] = 0.f;

  for (int pass = 0; pass < 2; ++pass) {
    const float* __restrict__ W2 = pass ? tW2 : sW2;
    const float* __restrict__ Hh = pass ? Ht  : Hs;
    for (int c0 = 0; c0 < 256; c0 += 64) {
      __syncthreads();
      for (int i = tid; i < 4096; i += 256) {
        int cc = i >> 6, ff = i & 63;
        wbuf[cc][ff] = W2[(size_t)(c0 + cc) * 65536 + (size_t)n * 64 + ff];
      }
      for (int i = tid; i < 4096; i += 256) {
        int l = i >> 6, cc = i & 63;
        hbuf[l][cc] = Hh[l * 256 + c0 + cc];
      }
      __syncthreads();
#pragma unroll
      for (int cc = 0; cc < 64; ++cc) {
        float w = wbuf[cc][f];
#pragma unroll
        for (int i = 0; i < 16; ++i)
          acc[i] += hbuf[lg * 16 + i][cc] * w;
      }
    }
  }
  float bias = sb2[n * 64 + f] + tb2[n * 64 + f];
  __syncthreads();
#pragma unroll
  for (int i = 0; i < 16; ++i) wbuf[f][lg * 16 + i] = acc[i] + bias;
  __syncthreads();
  for (int i = tid; i < 4096; i += 256) {
    int ff = i >> 6, l = i & 63;
    Vmat[(size_t)ff * 65536 + (size_t)n * 64 + l] = wbuf[ff][l];
  }
}

// ---------- obsT[l][n*4+df] = observation[n][df][l] ----------
__global__ __launch_bounds__(256) void transpose_obs(
    const float* __restrict__ obs, float* __restrict__ obsT)
{
  int n = blockIdx.x, t = threadIdx.x;
  int df = t >> 6, l = t & 63;
  obsT[l * 4096 + n * 4 + df] = obs[n * 256 + df * 64 + l];
}

// ---------- C(64,N) = A(64,K) @ W(K,N) + bias ----------
__global__ __launch_bounds__(256) void gemm64(
    const float* __restrict__ A, const float* __restrict__ W,
    const float* __restrict__ bias, float* __restrict__ C, int K, int N)
{
  int j0 = blockIdx.x * 64;
  __shared__ float At[64][65];
  __shared__ float Bt[64][65];
  int tid = threadIdx.x;
  int rg = tid >> 4, cg = tid & 15;
  float acc[4][4];
#pragma unroll
  for (int i = 0; i < 4; ++i)
#pragma unroll
    for (int j = 0; j < 4; ++j) acc[i][j] = 0.f;

  for (int k0 = 0; k0 < K; k0 += 64) {
    __syncthreads();
    for (int i = tid; i < 4096; i += 256) {
      int rr = i >> 6, cc = i & 63;
      At[rr][cc] = A[rr * K + k0 + cc];
      Bt[rr][cc] = W[(size_t)(k0 + rr) * N + j0 + cc];
    }
    __syncthreads();
#pragma unroll
    for (int kk = 0; kk < 64; ++kk) {
      float a[4], b[4];
#pragma unroll
      for (int i = 0; i < 4; ++i) a[i] = At[rg * 4 + i][kk];
#pragma unroll
      for (int j = 0; j < 4; ++j) b[j] = Bt[kk][cg * 4 + j];
#pragma unroll
      for (int i = 0; i < 4; ++i)
#pragma unroll
        for (int j = 0; j < 4; ++j) acc[i][j] += a[i] * b[j];
    }
  }
#pragma unroll
  for (int i = 0; i < 4; ++i)
#pragma unroll
    for (int j = 0; j < 4; ++j)
      C[(size_t)(rg * 4 + i) * N + j0 + cg * 4 + j] = acc[i][j] + bias[j0 + cg * 4 + j];
}

// ---------- in-place LN + relu over rows of width W ----------
__global__ __launch_bounds__(256) void ln_relu(
    float* __restrict__ X, const float* __restrict__ g,
    const float* __restrict__ b, int W)
{
  int row = blockIdx.x, tid = threadIdx.x;
  int per = W >> 8;
  float v[4];
  float s = 0.f, s2 = 0.f;
  for (int i = 0; i < per; ++i) {
    v[i] = X[row * W + i * 256 + tid];
    s += v[i]; s2 += v[i] * v[i];
  }
  __shared__ float rs[256], rs2[256];
  rs[tid] = s; rs2[tid] = s2;
  __syncthreads();
  for (int st = 128; st > 0; st >>= 1) {
    if (tid < st) { rs[tid] += rs[tid + st]; rs2[tid] += rs2[tid + st]; }
    __syncthreads();
  }
  float mu  = rs[0] / (float)W;
  float var = rs2[0] / (float)W - mu * mu;
  float inv = rsqrtf(var + EPS_C);
  for (int i = 0; i < per; ++i) {
    int col = i * 256 + tid;
    float y = (v[i] - mu) * inv * g[col] + b[col];
    X[row * W + col] = fmaxf(y, 0.f);
  }
}

// ---------- fused dilated graph-conv layer (flash-style online softmax) ----------
// Per block: one time index m, 64 output rows n0..n0+63.
// 3 attention instances: k=0 (a=b), k=1 forward, k=1 backward.
__global__ __launch_bounds__(256) void layer_kernel(
    const float* __restrict__ Vmat, const float* __restrict__ Bmat,
    const float* __restrict__ Xin, float* __restrict__ Xout,
    const float* __restrict__ Wf, const float* __restrict__ Wb,
    const float* __restrict__ bconv, int d, int gamma)
{
  int m  = blockIdx.x >> 4;
  int n0 = (blockIdx.x & 15) << 6;
  int tid = threadIdx.x;
  int rg = tid >> 4, cg = tid & 15;

  __shared__ float Va[64][65];   // V[a] rows -> then VaB = Va@B
  __shared__ float Qb[64][65];   // B / Vb tile / Xk tile / conv weight
  __shared__ float St[64][65];   // S->E tile ; P transfer
  __shared__ float rowm[64], rowl[64], rowsc[64];

  int ts = d - 1 + m * d;
  int tk = ts - 1;
  int cb = (gamma * ts) & 63;
  int ca = (gamma * tk) & 63;

  const int aIdx[3] = {cb, ca, cb};
  const int bIdx[3] = {cb, cb, ca};
  const int xti[3]  = {ts, tk, tk};

  float Z[4][4], msg[4][4];
#pragma unroll
  for (int i = 0; i < 4; ++i)
#pragma unroll
    for (int j = 0; j < 4; ++j) { Z[i][j] = 0.f; msg[i][j] = 0.f; }

  for (int inst = 0; inst < 3; ++inst) {
    const int a = aIdx[inst], b = bIdx[inst], t = xti[inst];
    if (tid < 64) { rowm[tid] = -1e30f; rowl[tid] = 0.f; }
    float P[4][4];
#pragma unroll
    for (int i = 0; i < 4; ++i)
#pragma unroll
      for (int j = 0; j < 4; ++j) P[i][j] = 0.f;

    // load V[a] rows (n0..n0+63) and B
    for (int i = tid; i < 4096; i += 256) {
      int rr = i >> 6, cc = i & 63;
      Va[rr][cc] = Vmat[(size_t)a * 65536 + (size_t)(n0 + rr) * 64 + cc];
      Qb[rr][cc] = Bmat[i];
    }
    __syncthreads();

    // VaB[n][p] = sum_l Va[n][l] * B[l][p]
    float vb[4][4];
#pragma unroll
    for (int i = 0; i < 4; ++i)
#pragma unroll
      for (int j = 0; j < 4; ++j) vb[i][j] = 0.f;
#pragma unroll
    for (int l = 0; l < 64; ++l) {
      float av[4], bv[4];
#pragma unroll
      for (int i = 0; i < 4; ++i) av[i] = Va[rg * 4 + i][l];
#pragma unroll
      for (int j = 0; j < 4; ++j) bv[j] = Qb[l][cg * 4 + j];
#pragma unroll
      for (int i = 0; i < 4; ++i)
#pragma unroll
        for (int j = 0; j < 4; ++j) vb[i][j] += av[i] * bv[j];
    }
    __syncthreads();
#pragma unroll
    for (int i = 0; i < 4; ++i)
#pragma unroll
      for (int j = 0; j < 4; ++j) Va[rg * 4 + i][cg * 4 + j] = vb[i][j];
    __syncthreads();

    for (int q0 = 0; q0 < 1024; q0 += 64) {
      // Vb tile
      for (int i = tid; i < 4096; i += 256) {
        int rr = i >> 6, cc = i & 63;
        Qb[rr][cc] = Vmat[(size_t)b * 65536 + (size_t)(q0 + rr) * 64 + cc];
      }
      __syncthreads();
      // S tile: S[n][q] = sum_p VaB[n][p] * Vb[q][p] ; threshold
      float sa[4][4];
#pragma unroll
      for (int i = 0; i < 4; ++i)
#pragma unroll
        for (int j = 0; j < 4; ++j) sa[i][j] = 0.f;
#pragma unroll
      for (int p = 0; p < 64; ++p) {
        float av[4], qv[4];
#pragma unroll
        for (int i = 0; i < 4; ++i) av[i] = Va[rg * 4 + i][p];
#pragma unroll
        for (int j = 0; j < 4; ++j) qv[j] = Qb[cg * 4 + j][p];
#pragma unroll
        for (int i = 0; i < 4; ++i)
#pragma unroll
          for (int j = 0; j < 4; ++j) sa[i][j] += av[i] * qv[j];
      }
#pragma unroll
      for (int i = 0; i < 4; ++i)
#pragma unroll
        for (int j = 0; j < 4; ++j) {
          float sv = sa[i][j];
          St[rg * 4 + i][cg * 4 + j] = (sv >= DELTA_C) ? sv : 0.f;
        }
      __syncthreads();
      // online softmax row stats (one thread per row)
      if (tid < 64) {
        float mold = rowm[tid];
        float tm = mold;
        for (int q = 0; q < 64; ++q) tm = fmaxf(tm, St[tid][q]);
        float sc = expf(mold - tm);
        float ssum = 0.f;
        for (int q = 0; q < 64; ++q) {
          float e = expf(St[tid][q] - tm);
          St[tid][q] = e;
          ssum += e;
        }
        rowl[tid] = rowl[tid] * sc + ssum;
        rowsc[tid] = sc;
        rowm[tid]  = tm;
      }
      __syncthreads();
      // Xk tile
      for (int i = tid; i < 4096; i += 256) {
        int rr = i >> 6, cc = i & 63;
        Qb[rr][cc] = Xin[(size_t)t * 65536 + (size_t)(q0 + rr) * 64 + cc];
      }
      __syncthreads();
      float scv[4];
#pragma unroll
      for (int i = 0; i < 4; ++i) scv[i] = rowsc[rg * 4 + i];
#pragma unroll
      for (int i = 0; i < 4; ++i)
#pragma unroll
        for (int j = 0; j < 4; ++j) P[i][j] *= scv[i];
#pragma unroll
      for (int q = 0; q < 64; ++q) {
        float ev[4], xv[4];
#pragma unroll
        for (int i = 0; i < 4; ++i) ev[i] = St[rg * 4 + i][q];
#pragma unroll
        for (int j = 0; j < 4; ++j) xv[j] = Qb[q][cg * 4 + j];
#pragma unroll
        for (int i = 0; i < 4; ++i)
#pragma unroll
          for (int j = 0; j < 4; ++j) P[i][j] += ev[i] * xv[j];
      }
      __syncthreads();
    }
    // normalize and transfer P to LDS; load conv weight
    float invl[4];
#pragma unroll
    for (int i = 0; i < 4; ++i) invl[i] = 1.f / rowl[rg * 4 + i];
#pragma unroll
    for (int i = 0; i < 4; ++i)
#pragma unroll
      for (int j = 0; j < 4; ++j) St[rg * 4 + i][cg * 4 + j] = P[i][j] * invl[i];
    for (int i = tid; i < 4096; i += 256) {
      float w;
      if (inst == 0)      w = Wf[i] + Wb[i];
      else if (inst == 1) w = Wf[4096 + i];
      else                w = Wb[4096 + i];
      Qb[i >> 6][i & 63] = w;
    }
    __syncthreads();
    // ma = P @ Wt
    float ma[4][4];
#pragma unroll
    for (int i = 0; i < 4; ++i)
#pragma unroll
      for (int j = 0; j < 4; ++j) ma[i][j] = 0.f;
#pragma unroll
    for (int ff = 0; ff < 64; ++ff) {
      float pv[4], wv[4];
#pragma unroll
      for (int i = 0; i < 4; ++i) pv[i] = St[rg * 4 + i][ff];
#pragma unroll
      for (int j = 0; j < 4; ++j) wv[j] = Qb[ff][cg * 4 + j];
#pragma unroll
      for (int i = 0; i < 4; ++i)
#pragma unroll
        for (int j = 0; j < 4; ++j) ma[i][j] += pv[i] * wv[j];
    }
    if (inst == 0) {
#pragma unroll
      for (int i = 0; i < 4; ++i)
#pragma unroll
        for (int j = 0; j < 4; ++j) Z[i][j] += tanhf(ma[i][j] + bconv[cg * 4 + j]);
    } else if (inst == 1) {
#pragma unroll
      for (int i = 0; i < 4; ++i)
#pragma unroll
        for (int j = 0; j < 4; ++j) msg[i][j] = ma[i][j];
    } else {
#pragma unroll
      for (int i = 0; i < 4; ++i)
#pragma unroll
        for (int j = 0; j < 4; ++j)
          Z[i][j] += tanhf(msg[i][j] + ma[i][j] + bconv[cg * 4 + j]);
    }
    __syncthreads();
  }
#pragma unroll
  for (int i = 0; i < 4; ++i)
#pragma unroll
    for (int j = 0; j < 4; ++j)
      Xout[(size_t)m * 65536 + (size_t)(n0 + rg * 4 + i) * 64 + cg * 4 + j] = Z[i][j];
}

__global__ __launch_bounds__(256) void copy_out_k(
    const float* __restrict__ src, float* __restrict__ dst, int n)
{
  int i = blockIdx.x * 256 + threadIdx.x;
  if (i < n) dst[i] = src[i];
}

extern "C" void kernel_launch(void* const* d_in, const int* in_sizes, int n_in,
                              void* d_out, int out_size, void* d_ws, size_t ws_size,
                              hipStream_t stream)
{
  const float* observation   = (const float*)d_in[0];
  const float* time_features = (const float*)d_in[1];
  const float* layer_initial = (const float*)d_in[2];
  const float* sW1   = (const float*)d_in[3];
  const float* sb1   = (const float*)d_in[4];
  const float* s_ln_g = (const float*)d_in[5];
  const float* s_ln_b = (const float*)d_in[6];
  const float* sW2   = (const float*)d_in[7];
  const float* sb2   = (const float*)d_in[8];
  const float* tW1   = (const float*)d_in[9];
  const float* tb1   = (const float*)d_in[10];
  const float* t_ln_g = (const float*)d_in[11];
  const float* t_ln_b = (const float*)d_in[12];
  const float* tW2   = (const float*)d_in[13];
  const float* tb2   = (const float*)d_in[14];
  const float* Bmat  = (const float*)d_in[15];
  const float* fW1   = (const float*)d_in[16];
  const float* fb1   = (const float*)d_in[17];
  const float* f1g   = (const float*)d_in[18];
  const float* f1b   = (const float*)d_in[19];
  const float* fW2   = (const float*)d_in[20];
  const float* fb2   = (const float*)d_in[21];
  const float* f2g   = (const float*)d_in[22];
  const float* f2b   = (const float*)d_in[23];
  const float* fW3   = (const float*)d_in[24];
  const float* fb3   = (const float*)d_in[25];
  const float* Wf    = (const float*)d_in[26];
  const float* Wb    = (const float*)d_in[27];
  const float* bconv = (const float*)d_in[28];
  float* out = (float*)d_out;

  float* ws   = (float*)d_ws;
  float* Vmat = ws;                      // 4,194,304 f
  float* X0   = Vmat + 4194304;          // 4,194,304 f
  float* X1   = X0 + 4194304;            // 2,097,152 f
  float* X2   = X1 + 2097152;            // 1,048,576 f
  float* Hs   = X2 + 1048576;            // 16,384 f
  float* Ht   = Hs + 16384;              // 16,384 f
  float* obsT = Ht + 16384;              // 262,144 f
  float* h1   = obsT + 262144;           // 65,536 f
  float* h2   = h1 + 65536;              // 32,768 f

  head_mlp<<<64, 256, 0, stream>>>(layer_initial, sW1, sb1, s_ln_g, s_ln_b, Hs, 1024);
  head_mlp<<<64, 256, 0, stream>>>(time_features, tW1, tb1, t_ln_g, t_ln_b, Ht, 8);
  emb_to_v<<<1024, 256, 0, stream>>>(Hs, Ht, sW2, sb2, tW2, tb2, Vmat);
  transpose_obs<<<1024, 256, 0, stream>>>(observation, obsT);
  gemm64<<<16, 256, 0, stream>>>(obsT, fW1, fb1, h1, 4096, 1024);
  ln_relu<<<64, 256, 0, stream>>>(h1, f1g, f1b, 1024);
  gemm64<<<8, 256, 0, stream>>>(h1, fW2, fb2, h2, 1024, 512);
  ln_relu<<<64, 256, 0, stream>>>(h2, f2g, f2b, 512);
  gemm64<<<1024, 256, 0, stream>>>(h2, fW3, fb3, X0, 512, 65536);

  layer_kernel<<<512, 256, 0, stream>>>(Vmat, Bmat, X0, X1, Wf, Wb, bconv, 2, 1);
  copy_out_k<<<256, 256, 0, stream>>>(X1 + (size_t)31 * 65536, out, 65536);
  layer_kernel<<<256, 256, 0, stream>>>(Vmat, Bmat, X1, X2, Wf, Wb, bconv, 2, 2);
  copy_out_k<<<256, 256, 0, stream>>>(X2 + (size_t)15 * 65536, out + 65536, 65536);
}

// Round 2
// 1337.764 us; speedup vs baseline: 2.8080x; 2.8080x over previous
//
#include <hip/hip_runtime.h>
#include <cstddef>

#define EPS_C   1e-5f
#define DELTA_C 0.05f

struct Pairs { int a[6]; int b[6]; int t[6]; };

// ---------- H = relu(LN(A @ W1 + b1)) ; A:(64,K), W1:(K,256), H:(64,256) ----------
__global__ __launch_bounds__(256) void head_mlp(
    const float* __restrict__ A, const float* __restrict__ W1,
    const float* __restrict__ b1, const float* __restrict__ g,
    const float* __restrict__ bb, float* __restrict__ H, int K)
{
  int row = blockIdx.x, j = threadIdx.x;
  float acc = b1[j];
  for (int c = 0; c < K; ++c) acc += A[row * K + c] * W1[c * 256 + j];
  __shared__ float rs[256], rs2[256];
  rs[j] = acc; rs2[j] = acc * acc;
  __syncthreads();
  for (int st = 128; st > 0; st >>= 1) {
    if (j < st) { rs[j] += rs[j + st]; rs2[j] += rs2[j + st]; }
    __syncthreads();
  }
  float mu  = rs[0] * (1.f / 256.f);
  float var = rs2[0] * (1.f / 256.f) - mu * mu;
  float y = (acc - mu) * rsqrtf(var + EPS_C) * g[j] + bb[j];
  H[row * 256 + j] = fmaxf(y, 0.f);
}

// ---------- Vs[c][n*64+l] = emb[l][n*64+60+c], c=0..3 ----------
__global__ __launch_bounds__(256) void emb_sel(
    const float* __restrict__ Hs, const float* __restrict__ Ht,
    const float* __restrict__ sW2, const float* __restrict__ sb2,
    const float* __restrict__ tW2, const float* __restrict__ tb2,
    float* __restrict__ Vs)
{
  int n = blockIdx.x, tid = threadIdx.x;
  int l = tid >> 2, c = tid & 3;
  __shared__ float wS[256][4], wT[256][4];
  {
    size_t base = (size_t)tid * 65536 + (size_t)n * 64 + 60;
    float4 a = *(const float4*)&sW2[base];
    float4 t4 = *(const float4*)&tW2[base];
    wS[tid][0] = a.x;  wS[tid][1] = a.y;  wS[tid][2] = a.z;  wS[tid][3] = a.w;
    wT[tid][0] = t4.x; wT[tid][1] = t4.y; wT[tid][2] = t4.z; wT[tid][3] = t4.w;
  }
  __syncthreads();
  const float* __restrict__ hs = Hs + l * 256;
  const float* __restrict__ ht = Ht + l * 256;
  float acc = 0.f;
  for (int k = 0; k < 256; k += 8) {
#pragma unroll
    for (int u = 0; u < 8; ++u)
      acc += hs[k + u] * wS[k + u][c] + ht[k + u] * wT[k + u][c];
  }
  int jj = n * 64 + 60 + c;
  Vs[(size_t)c * 65536 + (size_t)n * 64 + l] = acc + sb2[jj] + tb2[jj];
}

// ---------- obs4[c][n*4+df] = observation[n][df][60+c] ----------
__global__ __launch_bounds__(256) void obs_sel(
    const float* __restrict__ obs, float* __restrict__ obs4)
{
  int idx = blockIdx.x * 256 + threadIdx.x;   // 16384 total
  int c = idx >> 12;
  int r = idx & 4095;
  int n = r >> 2, df = r & 3;
  obs4[idx] = obs[n * 256 + df * 64 + 60 + c];
}

// ---------- part[(kc*4+c)*N + j] = sum_{k in chunk of 256} A[c][k0+k] * W[k0+k][j] ----------
__global__ __launch_bounds__(256) void skinny_part(
    const float* __restrict__ A, const float* __restrict__ W,
    float* __restrict__ part, int K, int N)
{
  int jblocks = N >> 8;
  int jb = blockIdx.x % jblocks;
  int kc = blockIdx.x / jblocks;
  int k0 = kc << 8;
  int tid = threadIdx.x;
  int j = (jb << 8) + tid;
  __shared__ float ARs[4][256];
#pragma unroll
  for (int c = 0; c < 4; ++c) ARs[c][tid] = A[c * K + k0 + tid];
  __syncthreads();
  float acc0 = 0.f, acc1 = 0.f, acc2 = 0.f, acc3 = 0.f;
  for (int kk = 0; kk < 256; kk += 8) {
    float w[8];
#pragma unroll
    for (int u = 0; u < 8; ++u) w[u] = W[(size_t)(k0 + kk + u) * N + j];
#pragma unroll
    for (int u = 0; u < 8; ++u) {
      acc0 += ARs[0][kk + u] * w[u];
      acc1 += ARs[1][kk + u] * w[u];
      acc2 += ARs[2][kk + u] * w[u];
      acc3 += ARs[3][kk + u] * w[u];
    }
  }
  part[(size_t)(kc * 4 + 0) * N + j] = acc0;
  part[(size_t)(kc * 4 + 1) * N + j] = acc1;
  part[(size_t)(kc * 4 + 2) * N + j] = acc2;
  part[(size_t)(kc * 4 + 3) * N + j] = acc3;
}

// ---------- out[c][j] = relu(LN(sum_parts + bias)) ; one block per row c ----------
template<int N_, int PARTS>
__global__ __launch_bounds__(256) void reduce_ln_relu(
    const float* __restrict__ part, const float* __restrict__ bias,
    const float* __restrict__ g, const float* __restrict__ bb,
    float* __restrict__ out)
{
  constexpr int PER = N_ >> 8;
  int c = blockIdx.x, tid = threadIdx.x;
  float x[PER];
  float s = 0.f, s2 = 0.f;
#pragma unroll
  for (int i = 0; i < PER; ++i) {
    int j = (i << 8) + tid;
    float v = bias[j];
    for (int p = 0; p < PARTS; ++p) v += part[(size_t)(p * 4 + c) * N_ + j];
    x[i] = v; s += v; s2 += v * v;
  }
  __shared__ float rs[256], rs2[256];
  rs[tid] = s; rs2[tid] = s2;
  __syncthreads();
  for (int st = 128; st > 0; st >>= 1) {
    if (tid < st) { rs[tid] += rs[tid + st]; rs2[tid] += rs2[tid + st]; }
    __syncthreads();
  }
  float mu  = rs[0] / (float)N_;
  float var = rs2[0] / (float)N_ - mu * mu;
  float inv = rsqrtf(var + EPS_C);
#pragma unroll
  for (int i = 0; i < PER; ++i) {
    int j = (i << 8) + tid;
    out[c * N_ + j] = fmaxf((x[i] - mu) * inv * g[j] + bb[j], 0.f);
  }
}

// ---------- Xr[c][j] = sum_k h2[c][k]*fW3[k][j] + fb3[j] ----------
__global__ __launch_bounds__(256) void big_w3(
    const float* __restrict__ h2, const float* __restrict__ fW3,
    const float* __restrict__ fb3, float* __restrict__ Xr)
{
  int tid = threadIdx.x;
  __shared__ float h2s[2048];
  for (int i = tid; i < 2048; i += 256) h2s[i] = h2[i];
  __syncthreads();
  int j = blockIdx.x * 256 + tid;
  float acc0 = 0.f, acc1 = 0.f, acc2 = 0.f, acc3 = 0.f;
  for (int k0 = 0; k0 < 512; k0 += 16) {
    float w[16];
#pragma unroll
    for (int u = 0; u < 16; ++u) w[u] = fW3[(size_t)(k0 + u) * 65536 + j];
#pragma unroll
    for (int u = 0; u < 16; ++u) {
      acc0 += h2s[k0 + u]        * w[u];
      acc1 += h2s[512 + k0 + u]  * w[u];
      acc2 += h2s[1024 + k0 + u] * w[u];
      acc3 += h2s[1536 + k0 + u] * w[u];
    }
  }
  float b = fb3[j];
  Xr[j]           = acc0 + b;
  Xr[65536 + j]   = acc1 + b;
  Xr[131072 + j]  = acc2 + b;
  Xr[196608 + j]  = acc3 + b;
}

// ---------- one attention pair: P = softmaxrow(thresh((V[a]@B)@V[b]^T)) @ X[t] ----------
// grid = npairs*16 ; block handles 64 rows of n.
__global__ __launch_bounds__(256) void attn_pair(
    const float* __restrict__ Vs, const float* __restrict__ Bmat,
    const float* __restrict__ Xbase, float* __restrict__ Pout, Pairs pr)
{
  int pi = blockIdx.x >> 4;
  int n0 = (blockIdx.x & 15) << 6;
  int tid = threadIdx.x;
  int rg = tid >> 4, cg = tid & 15;
  int a = pr.a[pi], b = pr.b[pi], t = pr.t[pi];

  __shared__ float Va[64][65];
  __shared__ float Qb[64][65];
  __shared__ float St[64][65];
  __shared__ float rowm[64], rowl[64], rowsc[64];

  for (int i = tid; i < 4096; i += 256) {
    int rr = i >> 6, cc = i & 63;
    Va[rr][cc] = Vs[(size_t)a * 65536 + (size_t)(n0 + rr) * 64 + cc];
    Qb[rr][cc] = Bmat[i];
  }
  if (tid < 64) { rowm[tid] = -1e30f; rowl[tid] = 0.f; }
  __syncthreads();

  // VaB = Va @ B
  float vb[4][4];
#pragma unroll
  for (int i = 0; i < 4; ++i)
#pragma unroll
    for (int j = 0; j < 4; ++j) vb[i][j] = 0.f;
#pragma unroll
  for (int l = 0; l < 64; ++l) {
    float av[4], bv[4];
#pragma unroll
    for (int i = 0; i < 4; ++i) av[i] = Va[rg * 4 + i][l];
#pragma unroll
    for (int j = 0; j < 4; ++j) bv[j] = Qb[l][cg * 4 + j];
#pragma unroll
    for (int i = 0; i < 4; ++i)
#pragma unroll
      for (int j = 0; j < 4; ++j) vb[i][j] += av[i] * bv[j];
  }
  __syncthreads();
#pragma unroll
  for (int i = 0; i < 4; ++i)
#pragma unroll
    for (int j = 0; j < 4; ++j) Va[rg * 4 + i][cg * 4 + j] = vb[i][j];
  __syncthreads();

  float P[4][4];
#pragma unroll
  for (int i = 0; i < 4; ++i)
#pragma unroll
    for (int j = 0; j < 4; ++j) P[i][j] = 0.f;

  for (int q0 = 0; q0 < 1024; q0 += 64) {
    for (int i = tid; i < 4096; i += 256) {
      int rr = i >> 6, cc = i & 63;
      Qb[rr][cc] = Vs[(size_t)b * 65536 + (size_t)(q0 + rr) * 64 + cc];
    }
    __syncthreads();
    // S tile + threshold
    float sa[4][4];
#pragma unroll
    for (int i = 0; i < 4; ++i)
#pragma unroll
      for (int j = 0; j < 4; ++j) sa[i][j] = 0.f;
#pragma unroll
    for (int p = 0; p < 64; ++p) {
      float av[4], qv[4];
#pragma unroll
      for (int i = 0; i < 4; ++i) av[i] = Va[rg * 4 + i][p];
#pragma unroll
      for (int j = 0; j < 4; ++j) qv[j] = Qb[cg * 4 + j][p];
#pragma unroll
      for (int i = 0; i < 4; ++i)
#pragma unroll
        for (int j = 0; j < 4; ++j) sa[i][j] += av[i] * qv[j];
    }
#pragma unroll
    for (int i = 0; i < 4; ++i)
#pragma unroll
      for (int j = 0; j < 4; ++j) {
        float sv = sa[i][j];
        St[rg * 4 + i][cg * 4 + j] = (sv >= DELTA_C) ? sv : 0.f;
      }
    __syncthreads();
    // wave-parallel online softmax: 4 lanes per row
    {
      int r = tid >> 2, sub = tid & 3;
      float tm = -1e30f;
#pragma unroll
      for (int jj = 0; jj < 16; ++jj) tm = fmaxf(tm, St[r][sub * 16 + jj]);
      tm = fmaxf(tm, __shfl_xor(tm, 1));
      tm = fmaxf(tm, __shfl_xor(tm, 2));
      float mold = rowm[r];
      float mnew = fmaxf(mold, tm);
      float ssum = 0.f;
#pragma unroll
      for (int jj = 0; jj < 16; ++jj) {
        float e = __expf(St[r][sub * 16 + jj] - mnew);
        St[r][sub * 16 + jj] = e;
        ssum += e;
      }
      ssum += __shfl_xor(ssum, 1);
      ssum += __shfl_xor(ssum, 2);
      if (sub == 0) {
        float sc = __expf(mold - mnew);
        rowsc[r] = sc;
        rowl[r] = rowl[r] * sc + ssum;
        rowm[r] = mnew;
      }
    }
    // X tile (Qb free: S-GEMM finished before last sync)
    for (int i = tid; i < 4096; i += 256) {
      int rr = i >> 6, cc = i & 63;
      Qb[rr][cc] = Xbase[(size_t)t * 65536 + (size_t)(q0 + rr) * 64 + cc];
    }
    __syncthreads();
    float scv[4];
#pragma unroll
    for (int i = 0; i < 4; ++i) scv[i] = rowsc[rg * 4 + i];
#pragma unroll
    for (int i = 0; i < 4; ++i)
#pragma unroll
      for (int j = 0; j < 4; ++j) P[i][j] *= scv[i];
#pragma unroll
    for (int q = 0; q < 64; ++q) {
      float ev[4], xv[4];
#pragma unroll
      for (int i = 0; i < 4; ++i) ev[i] = St[rg * 4 + i][q];
#pragma unroll
      for (int j = 0; j < 4; ++j) xv[j] = Qb[q][cg * 4 + j];
#pragma unroll
      for (int i = 0; i < 4; ++i)
#pragma unroll
        for (int j = 0; j < 4; ++j) P[i][j] += ev[i] * xv[j];
    }
    __syncthreads();
  }
  float invl[4];
#pragma unroll
  for (int i = 0; i < 4; ++i) invl[i] = 1.f / rowl[rg * 4 + i];
#pragma unroll
  for (int i = 0; i < 4; ++i)
#pragma unroll
    for (int j = 0; j < 4; ++j)
      Pout[(size_t)pi * 65536 + (size_t)(n0 + rg * 4 + i) * 64 + cg * 4 + j] =
          P[i][j] * invl[i];
}

// ---------- Z[mm] = tanh(P0@(Wf0+Wb0)+b) + tanh(P1@Wf1 + P2@Wb1 + b) ----------
__global__ __launch_bounds__(256) void combine_z(
    const float* __restrict__ Pm, const float* __restrict__ Wf,
    const float* __restrict__ Wb, const float* __restrict__ bconv,
    float* __restrict__ dst0, float* __restrict__ dst1, float* __restrict__ extra1)
{
  int mm = blockIdx.x >> 4;
  int n0 = (blockIdx.x & 15) << 6;
  int tid = threadIdx.x;
  int rg = tid >> 4, cg = tid & 15;
  __shared__ float W0[64][65], W1[64][65], W2[64][65];
  __shared__ float P0[64][65], P1[64][65], P2[64][65];
  for (int i = tid; i < 4096; i += 256) {
    int rr = i >> 6, cc = i & 63;
    W0[rr][cc] = Wf[i] + Wb[i];
    W1[rr][cc] = Wf[4096 + i];
    W2[rr][cc] = Wb[4096 + i];
    P0[rr][cc] = Pm[(size_t)(3 * mm + 0) * 65536 + (size_t)n0 * 64 + i];
    P1[rr][cc] = Pm[(size_t)(3 * mm + 1) * 65536 + (size_t)n0 * 64 + i];
    P2[rr][cc] = Pm[(size_t)(3 * mm + 2) * 65536 + (size_t)n0 * 64 + i];
  }
  __syncthreads();
  float a0[4][4], a1[4][4], a2[4][4];
#pragma unroll
  for (int i = 0; i < 4; ++i)
#pragma unroll
    for (int j = 0; j < 4; ++j) { a0[i][j] = 0.f; a1[i][j] = 0.f; a2[i][j] = 0.f; }
#pragma unroll
  for (int ff = 0; ff < 64; ++ff) {
    float p0[4], p1[4], p2[4], w0[4], w1[4], w2[4];
#pragma unroll
    for (int i = 0; i < 4; ++i) {
      p0[i] = P0[rg * 4 + i][ff];
      p1[i] = P1[rg * 4 + i][ff];
      p2[i] = P2[rg * 4 + i][ff];
    }
#pragma unroll
    for (int j = 0; j < 4; ++j) {
      w0[j] = W0[ff][cg * 4 + j];
      w1[j] = W1[ff][cg * 4 + j];
      w2[j] = W2[ff][cg * 4 + j];
    }
#pragma unroll
    for (int i = 0; i < 4; ++i)
#pragma unroll
      for (int j = 0; j < 4; ++j) {
        a0[i][j] += p0[i] * w0[j];
        a1[i][j] += p1[i] * w1[j];
        a2[i][j] += p2[i] * w2[j];
      }
  }
  float* dst = (mm == 0) ? dst0 : dst1;
#pragma unroll
  for (int i = 0; i < 4; ++i)
#pragma unroll
    for (int j = 0; j < 4; ++j) {
      float bc = bconv[cg * 4 + j];
      float z = tanhf(a0[i][j] + bc) + tanhf(a1[i][j] + a2[i][j] + bc);
      size_t idx = (size_t)(n0 + rg * 4 + i) * 64 + cg * 4 + j;
      dst[idx] = z;
      if (mm == 1 && extra1) extra1[idx] = z;
    }
}

extern "C" void kernel_launch(void* const* d_in, const int* in_sizes, int n_in,
                              void* d_out, int out_size, void* d_ws, size_t ws_size,
                              hipStream_t stream)
{
  const float* observation   = (const float*)d_in[0];
  const float* time_features = (const float*)d_in[1];
  const float* layer_initial = (const float*)d_in[2];
  const float* sW1   = (const float*)d_in[3];
  const float* sb1   = (const float*)d_in[4];
  const float* s_ln_g = (const float*)d_in[5];
  const float* s_ln_b = (const float*)d_in[6];
  const float* sW2   = (const float*)d_in[7];
  const float* sb2   = (const float*)d_in[8];
  const float* tW1   = (const float*)d_in[9];
  const float* tb1   = (const float*)d_in[10];
  const float* t_ln_g = (const float*)d_in[11];
  const float* t_ln_b = (const float*)d_in[12];
  const float* tW2   = (const float*)d_in[13];
  const float* tb2   = (const float*)d_in[14];
  const float* Bmat  = (const float*)d_in[15];
  const float* fW1   = (const float*)d_in[16];
  const float* fb1   = (const float*)d_in[17];
  const float* f1g   = (const float*)d_in[18];
  const float* f1b   = (const float*)d_in[19];
  const float* fW2   = (const float*)d_in[20];
  const float* fb2   = (const float*)d_in[21];
  const float* f2g   = (const float*)d_in[22];
  const float* f2b   = (const float*)d_in[23];
  const float* fW3   = (const float*)d_in[24];
  const float* fb3   = (const float*)d_in[25];
  const float* Wf    = (const float*)d_in[26];
  const float* Wb    = (const float*)d_in[27];
  const float* bconv = (const float*)d_in[28];
  float* out = (float*)d_out;

  float* ws   = (float*)d_ws;
  float* Hs   = ws;                 // 16384
  float* Ht   = Hs   + 16384;       // 16384
  float* Vs   = Ht   + 16384;       // 262144
  float* obs4 = Vs   + 262144;      // 16384
  float* part = obs4 + 16384;       // 65536
  float* h1   = part + 65536;       // 4096
  float* h2   = h1   + 4096;        // 2048
  float* Xr   = h2   + 2048;        // 262144
  float* Pm   = Xr   + 262144;      // 589824 (9 x 65536)
  float* Z1   = Pm   + 589824;      // 131072 (2 x 65536)

  head_mlp<<<64, 256, 0, stream>>>(layer_initial, sW1, sb1, s_ln_g, s_ln_b, Hs, 1024);
  head_mlp<<<64, 256, 0, stream>>>(time_features, tW1, tb1, t_ln_g, t_ln_b, Ht, 8);
  emb_sel<<<1024, 256, 0, stream>>>(Hs, Ht, sW2, sb2, tW2, tb2, Vs);

  obs_sel<<<64, 256, 0, stream>>>(observation, obs4);
  skinny_part<<<64, 256, 0, stream>>>(obs4, fW1, part, 4096, 1024);   // 16 kc x 4 jb
  reduce_ln_relu<1024, 16><<<4, 256, 0, stream>>>(part, fb1, f1g, f1b, h1);
  skinny_part<<<8, 256, 0, stream>>>(h1, fW2, part, 1024, 512);       // 4 kc x 2 jb
  reduce_ln_relu<512, 4><<<4, 256, 0, stream>>>(part, fb2, f2g, f2b, h2);
  big_w3<<<256, 256, 0, stream>>>(h2, fW3, fb3, Xr);

  // layer-1, m=30 (cols 60/61, X rows 0/1) and m=31 (cols 62/63, X rows 2/3)
  Pairs pA;
  pA.a[0]=1; pA.b[0]=1; pA.t[0]=1;   // k=0, m=30: A(61,61) @ X[61]
  pA.a[1]=0; pA.b[1]=1; pA.t[1]=0;   // k=1, m=30: A(60,61) @ X[60]
  pA.a[2]=1; pA.b[2]=0; pA.t[2]=0;   // k=1, m=30: A(61,60) @ X[60]
  pA.a[3]=3; pA.b[3]=3; pA.t[3]=3;   // k=0, m=31: A(63,63) @ X[63]
  pA.a[4]=2; pA.b[4]=3; pA.t[4]=2;   // k=1, m=31: A(62,63) @ X[62]
  pA.a[5]=3; pA.b[5]=2; pA.t[5]=2;   // k=1, m=31: A(63,62) @ X[62]
  attn_pair<<<96, 256, 0, stream>>>(Vs, Bmat, Xr, Pm, pA);
  combine_z<<<32, 256, 0, stream>>>(Pm, Wf, Wb, bconv, Z1, Z1 + 65536, out);

  // layer-2, m=15: cols 62(=2)/60(=0), X = Z1 rows {0: m30, 1: m31}
  Pairs pB;
  pB.a[0]=2; pB.b[0]=2; pB.t[0]=1;   // k=0: A(62,62) @ X1[31]
  pB.a[1]=0; pB.b[1]=2; pB.t[1]=0;   // k=1: A(60,62) @ X1[30]
  pB.a[2]=2; pB.b[2]=0; pB.t[2]=0;   // k=1: A(62,60) @ X1[30]
  pB.a[3]=pB.a[4]=pB.a[5]=0; pB.b[3]=pB.b[4]=pB.b[5]=0; pB.t[3]=pB.t[4]=pB.t[5]=0;
  attn_pair<<<48, 256, 0, stream>>>(Vs, Bmat, Z1, Pm + 6 * 65536, pB);
  combine_z<<<16, 256, 0, stream>>>(Pm + 6 * 65536, Wf, Wb, bconv,
                                    out + 65536, out + 65536, nullptr);
}

// Round 3
// 1118.667 us; speedup vs baseline: 3.3579x; 1.1959x over previous
//
#include <hip/hip_runtime.h>
#include <cstddef>

#define EPS_C   1e-5f
#define DELTA_C 0.05f

struct Pairs { int a[6]; int b[6]; int t[6]; };

// ---------- H = relu(LN(A @ W1 + b1)) ; A:(64,K), W1:(K,256), H:(64,256) ----------
template<int K>
__global__ __launch_bounds__(256) void head_mlp_t(
    const float* __restrict__ A, const float* __restrict__ W1,
    const float* __restrict__ b1, const float* __restrict__ g,
    const float* __restrict__ bb, float* __restrict__ H)
{
  int row = blockIdx.x, j = threadIdx.x;
  __shared__ float As[K];
  for (int i = j; i < K; i += 256) As[i] = A[row * K + i];
  __syncthreads();

  float a0 = 0.f, a1 = 0.f, a2 = 0.f, a3 = 0.f;
  const float* __restrict__ Wp = W1 + j;
#pragma unroll 2
  for (int c = 0; c < K; c += 8) {
    float w0 = Wp[(size_t)(c + 0) * 256];
    float w1 = Wp[(size_t)(c + 1) * 256];
    float w2 = Wp[(size_t)(c + 2) * 256];
    float w3 = Wp[(size_t)(c + 3) * 256];
    float w4 = Wp[(size_t)(c + 4) * 256];
    float w5 = Wp[(size_t)(c + 5) * 256];
    float w6 = Wp[(size_t)(c + 6) * 256];
    float w7 = Wp[(size_t)(c + 7) * 256];
    a0 += As[c + 0] * w0 + As[c + 4] * w4;
    a1 += As[c + 1] * w1 + As[c + 5] * w5;
    a2 += As[c + 2] * w2 + As[c + 6] * w6;
    a3 += As[c + 3] * w3 + As[c + 7] * w7;
  }
  float acc = ((a0 + a1) + (a2 + a3)) + b1[j];

  __shared__ float rs[256], rs2[256];
  rs[j] = acc; rs2[j] = acc * acc;
  __syncthreads();
  for (int st = 128; st > 0; st >>= 1) {
    if (j < st) { rs[j] += rs[j + st]; rs2[j] += rs2[j + st]; }
    __syncthreads();
  }
  float mu  = rs[0] * (1.f / 256.f);
  float var = rs2[0] * (1.f / 256.f) - mu * mu;
  float y = (acc - mu) * rsqrtf(var + EPS_C) * g[j] + bb[j];
  H[row * 256 + j] = fmaxf(y, 0.f);
}

// ---------- Vs[c][n*64+l] = emb[l][n*64+60+c], c=0..3 ----------
__global__ __launch_bounds__(256) void emb_sel(
    const float* __restrict__ Hs, const float* __restrict__ Ht,
    const float* __restrict__ sW2, const float* __restrict__ sb2,
    const float* __restrict__ tW2, const float* __restrict__ tb2,
    float* __restrict__ Vs)
{
  int n = blockIdx.x, tid = threadIdx.x;
  int l = tid >> 2, c = tid & 3;
  __shared__ float wS[256][4], wT[256][4];
  {
    size_t base = (size_t)tid * 65536 + (size_t)n * 64 + 60;
    float4 a = *(const float4*)&sW2[base];
    float4 t4 = *(const float4*)&tW2[base];
    wS[tid][0] = a.x;  wS[tid][1] = a.y;  wS[tid][2] = a.z;  wS[tid][3] = a.w;
    wT[tid][0] = t4.x; wT[tid][1] = t4.y; wT[tid][2] = t4.z; wT[tid][3] = t4.w;
  }
  __syncthreads();
  const float* __restrict__ hs = Hs + l * 256;
  const float* __restrict__ ht = Ht + l * 256;
  float acc = 0.f;
  for (int k = 0; k < 256; k += 8) {
#pragma unroll
    for (int u = 0; u < 8; ++u)
      acc += hs[k + u] * wS[k + u][c] + ht[k + u] * wT[k + u][c];
  }
  int jj = n * 64 + 60 + c;
  Vs[(size_t)c * 65536 + (size_t)n * 64 + l] = acc + sb2[jj] + tb2[jj];
}

// ---------- obs4[c][n*4+df] = observation[n][df][60+c] ----------
__global__ __launch_bounds__(256) void obs_sel(
    const float* __restrict__ obs, float* __restrict__ obs4)
{
  int idx = blockIdx.x * 256 + threadIdx.x;   // 16384 total
  int c = idx >> 12;
  int r = idx & 4095;
  int n = r >> 2, df = r & 3;
  obs4[idx] = obs[n * 256 + df * 64 + 60 + c];
}

// ---------- part[(kc*4+c)*N + j] = sum_{k in chunk of 256} A[c][k0+k] * W[k0+k][j] ----------
__global__ __launch_bounds__(256) void skinny_part(
    const float* __restrict__ A, const float* __restrict__ W,
    float* __restrict__ part, int K, int N)
{
  int jblocks = N >> 8;
  int jb = blockIdx.x % jblocks;
  int kc = blockIdx.x / jblocks;
  int k0 = kc << 8;
  int tid = threadIdx.x;
  int j = (jb << 8) + tid;
  __shared__ float ARs[4][256];
#pragma unroll
  for (int c = 0; c < 4; ++c) ARs[c][tid] = A[c * K + k0 + tid];
  __syncthreads();
  float acc0 = 0.f, acc1 = 0.f, acc2 = 0.f, acc3 = 0.f;
  for (int kk = 0; kk < 256; kk += 8) {
    float w[8];
#pragma unroll
    for (int u = 0; u < 8; ++u) w[u] = W[(size_t)(k0 + kk + u) * N + j];
#pragma unroll
    for (int u = 0; u < 8; ++u) {
      acc0 += ARs[0][kk + u] * w[u];
      acc1 += ARs[1][kk + u] * w[u];
      acc2 += ARs[2][kk + u] * w[u];
      acc3 += ARs[3][kk + u] * w[u];
    }
  }
  part[(size_t)(kc * 4 + 0) * N + j] = acc0;
  part[(size_t)(kc * 4 + 1) * N + j] = acc1;
  part[(size_t)(kc * 4 + 2) * N + j] = acc2;
  part[(size_t)(kc * 4 + 3) * N + j] = acc3;
}

// ---------- out[c][j] = relu(LN(sum_parts + bias)) ; one block per row c ----------
template<int N_, int PARTS>
__global__ __launch_bounds__(256) void reduce_ln_relu(
    const float* __restrict__ part, const float* __restrict__ bias,
    const float* __restrict__ g, const float* __restrict__ bb,
    float* __restrict__ out)
{
  constexpr int PER = N_ >> 8;
  int c = blockIdx.x, tid = threadIdx.x;
  float x[PER];
  float s = 0.f, s2 = 0.f;
#pragma unroll
  for (int i = 0; i < PER; ++i) {
    int j = (i << 8) + tid;
    float v = bias[j];
#pragma unroll
    for (int p = 0; p < PARTS; ++p) v += part[(size_t)(p * 4 + c) * N_ + j];
    x[i] = v; s += v; s2 += v * v;
  }
  __shared__ float rs[256], rs2[256];
  rs[tid] = s; rs2[tid] = s2;
  __syncthreads();
  for (int st = 128; st > 0; st >>= 1) {
    if (tid < st) { rs[tid] += rs[tid + st]; rs2[tid] += rs2[tid + st]; }
    __syncthreads();
  }
  float mu  = rs[0] / (float)N_;
  float var = rs2[0] / (float)N_ - mu * mu;
  float inv = rsqrtf(var + EPS_C);
#pragma unroll
  for (int i = 0; i < PER; ++i) {
    int j = (i << 8) + tid;
    out[c * N_ + j] = fmaxf((x[i] - mu) * inv * g[j] + bb[j], 0.f);
  }
}

// ---------- Xr[c][j] = sum_k h2[c][k]*fW3[k][j] + fb3[j] ----------
__global__ __launch_bounds__(256) void big_w3(
    const float* __restrict__ h2, const float* __restrict__ fW3,
    const float* __restrict__ fb3, float* __restrict__ Xr)
{
  int tid = threadIdx.x;
  __shared__ float h2s[2048];
  for (int i = tid; i < 2048; i += 256) h2s[i] = h2[i];
  __syncthreads();
  int j = blockIdx.x * 256 + tid;
  float acc0 = 0.f, acc1 = 0.f, acc2 = 0.f, acc3 = 0.f;
  for (int k0 = 0; k0 < 512; k0 += 16) {
    float w[16];
#pragma unroll
    for (int u = 0; u < 16; ++u) w[u] = fW3[(size_t)(k0 + u) * 65536 + j];
#pragma unroll
    for (int u = 0; u < 16; ++u) {
      acc0 += h2s[k0 + u]        * w[u];
      acc1 += h2s[512 + k0 + u]  * w[u];
      acc2 += h2s[1024 + k0 + u] * w[u];
      acc3 += h2s[1536 + k0 + u] * w[u];
    }
  }
  float b = fb3[j];
  Xr[j]           = acc0 + b;
  Xr[65536 + j]   = acc1 + b;
  Xr[131072 + j]  = acc2 + b;
  Xr[196608 + j]  = acc3 + b;
}

// ---------- one attention pair: P = softmaxrow(thresh((V[a]@B)@V[b]^T)) @ X[t] ----------
__global__ __launch_bounds__(256) void attn_pair(
    const float* __restrict__ Vs, const float* __restrict__ Bmat,
    const float* __restrict__ Xbase, float* __restrict__ Pout, Pairs pr)
{
  int pi = blockIdx.x >> 4;
  int n0 = (blockIdx.x & 15) << 6;
  int tid = threadIdx.x;
  int rg = tid >> 4, cg = tid & 15;
  int a = pr.a[pi], b = pr.b[pi], t = pr.t[pi];

  __shared__ float Va[64][65];
  __shared__ float Qb[64][65];
  __shared__ float St[64][65];
  __shared__ float rowm[64], rowl[64], rowsc[64];

  for (int i = tid; i < 4096; i += 256) {
    int rr = i >> 6, cc = i & 63;
    Va[rr][cc] = Vs[(size_t)a * 65536 + (size_t)(n0 + rr) * 64 + cc];
    Qb[rr][cc] = Bmat[i];
  }
  if (tid < 64) { rowm[tid] = -1e30f; rowl[tid] = 0.f; }
  __syncthreads();

  // VaB = Va @ B
  float vb[4][4];
#pragma unroll
  for (int i = 0; i < 4; ++i)
#pragma unroll
    for (int j = 0; j < 4; ++j) vb[i][j] = 0.f;
#pragma unroll
  for (int l = 0; l < 64; ++l) {
    float av[4], bv[4];
#pragma unroll
    for (int i = 0; i < 4; ++i) av[i] = Va[rg * 4 + i][l];
#pragma unroll
    for (int j = 0; j < 4; ++j) bv[j] = Qb[l][cg * 4 + j];
#pragma unroll
    for (int i = 0; i < 4; ++i)
#pragma unroll
      for (int j = 0; j < 4; ++j) vb[i][j] += av[i] * bv[j];
  }
  __syncthreads();
#pragma unroll
  for (int i = 0; i < 4; ++i)
#pragma unroll
    for (int j = 0; j < 4; ++j) Va[rg * 4 + i][cg * 4 + j] = vb[i][j];
  __syncthreads();

  float P[4][4];
#pragma unroll
  for (int i = 0; i < 4; ++i)
#pragma unroll
    for (int j = 0; j < 4; ++j) P[i][j] = 0.f;

  for (int q0 = 0; q0 < 1024; q0 += 64) {
    for (int i = tid; i < 4096; i += 256) {
      int rr = i >> 6, cc = i & 63;
      Qb[rr][cc] = Vs[(size_t)b * 65536 + (size_t)(q0 + rr) * 64 + cc];
    }
    __syncthreads();
    // S tile + threshold
    float sa[4][4];
#pragma unroll
    for (int i = 0; i < 4; ++i)
#pragma unroll
      for (int j = 0; j < 4; ++j) sa[i][j] = 0.f;
#pragma unroll
    for (int p = 0; p < 64; ++p) {
      float av[4], qv[4];
#pragma unroll
      for (int i = 0; i < 4; ++i) av[i] = Va[rg * 4 + i][p];
#pragma unroll
      for (int j = 0; j < 4; ++j) qv[j] = Qb[cg * 4 + j][p];
#pragma unroll
      for (int i = 0; i < 4; ++i)
#pragma unroll
        for (int j = 0; j < 4; ++j) sa[i][j] += av[i] * qv[j];
    }
#pragma unroll
    for (int i = 0; i < 4; ++i)
#pragma unroll
      for (int j = 0; j < 4; ++j) {
        float sv = sa[i][j];
        St[rg * 4 + i][cg * 4 + j] = (sv >= DELTA_C) ? sv : 0.f;
      }
    __syncthreads();
    // wave-parallel online softmax: 4 lanes per row
    {
      int r = tid >> 2, sub = tid & 3;
      float tm = -1e30f;
#pragma unroll
      for (int jj = 0; jj < 16; ++jj) tm = fmaxf(tm, St[r][sub * 16 + jj]);
      tm = fmaxf(tm, __shfl_xor(tm, 1));
      tm = fmaxf(tm, __shfl_xor(tm, 2));
      float mold = rowm[r];
      float mnew = fmaxf(mold, tm);
      float ssum = 0.f;
#pragma unroll
      for (int jj = 0; jj < 16; ++jj) {
        float e = __expf(St[r][sub * 16 + jj] - mnew);
        St[r][sub * 16 + jj] = e;
        ssum += e;
      }
      ssum += __shfl_xor(ssum, 1);
      ssum += __shfl_xor(ssum, 2);
      if (sub == 0) {
        float sc = __expf(mold - mnew);
        rowsc[r] = sc;
        rowl[r] = rowl[r] * sc + ssum;
        rowm[r] = mnew;
      }
    }
    // X tile
    for (int i = tid; i < 4096; i += 256) {
      int rr = i >> 6, cc = i & 63;
      Qb[rr][cc] = Xbase[(size_t)t * 65536 + (size_t)(q0 + rr) * 64 + cc];
    }
    __syncthreads();
    float scv[4];
#pragma unroll
    for (int i = 0; i < 4; ++i) scv[i] = rowsc[rg * 4 + i];
#pragma unroll
    for (int i = 0; i < 4; ++i)
#pragma unroll
      for (int j = 0; j < 4; ++j) P[i][j] *= scv[i];
#pragma unroll
    for (int q = 0; q < 64; ++q) {
      float ev[4], xv[4];
#pragma unroll
      for (int i = 0; i < 4; ++i) ev[i] = St[rg * 4 + i][q];
#pragma unroll
      for (int j = 0; j < 4; ++j) xv[j] = Qb[q][cg * 4 + j];
#pragma unroll
      for (int i = 0; i < 4; ++i)
#pragma unroll
        for (int j = 0; j < 4; ++j) P[i][j] += ev[i] * xv[j];
    }
    __syncthreads();
  }
  float invl[4];
#pragma unroll
  for (int i = 0; i < 4; ++i) invl[i] = 1.f / rowl[rg * 4 + i];
#pragma unroll
  for (int i = 0; i < 4; ++i)
#pragma unroll
    for (int j = 0; j < 4; ++j)
      Pout[(size_t)pi * 65536 + (size_t)(n0 + rg * 4 + i) * 64 + cg * 4 + j] =
          P[i][j] * invl[i];
}

// ---------- Z[mm] = tanh(P0@(Wf0+Wb0)+b) + tanh(P1@Wf1 + P2@Wb1 + b) ----------
__global__ __launch_bounds__(256) void combine_z(
    const float* __restrict__ Pm, const float* __restrict__ Wf,
    const float* __restrict__ Wb, const float* __restrict__ bconv,
    float* __restrict__ dst0, float* __restrict__ dst1, float* __restrict__ extra1)
{
  int mm = blockIdx.x >> 4;
  int n0 = (blockIdx.x & 15) << 6;
  int tid = threadIdx.x;
  int rg = tid >> 4, cg = tid & 15;
  __shared__ float W0[64][65], W1[64][65], W2[64][65];
  __shared__ float P0[64][65], P1[64][65], P2[64][65];
  for (int i = tid; i < 4096; i += 256) {
    int rr = i >> 6, cc = i & 63;
    W0[rr][cc] = Wf[i] + Wb[i];
    W1[rr][cc] = Wf[4096 + i];
    W2[rr][cc] = Wb[4096 + i];
    P0[rr][cc] = Pm[(size_t)(3 * mm + 0) * 65536 + (size_t)n0 * 64 + i];
    P1[rr][cc] = Pm[(size_t)(3 * mm + 1) * 65536 + (size_t)n0 * 64 + i];
    P2[rr][cc] = Pm[(size_t)(3 * mm + 2) * 65536 + (size_t)n0 * 64 + i];
  }
  __syncthreads();
  float a0[4][4], a1[4][4], a2[4][4];
#pragma unroll
  for (int i = 0; i < 4; ++i)
#pragma unroll
    for (int j = 0; j < 4; ++j) { a0[i][j] = 0.f; a1[i][j] = 0.f; a2[i][j] = 0.f; }
#pragma unroll
  for (int ff = 0; ff < 64; ++ff) {
    float p0[4], p1[4], p2[4], w0[4], w1[4], w2[4];
#pragma unroll
    for (int i = 0; i < 4; ++i) {
      p0[i] = P0[rg * 4 + i][ff];
      p1[i] = P1[rg * 4 + i][ff];
      p2[i] = P2[rg * 4 + i][ff];
    }
#pragma unroll
    for (int j = 0; j < 4; ++j) {
      w0[j] = W0[ff][cg * 4 + j];
      w1[j] = W1[ff][cg * 4 + j];
      w2[j] = W2[ff][cg * 4 + j];
    }
#pragma unroll
    for (int i = 0; i < 4; ++i)
#pragma unroll
      for (int j = 0; j < 4; ++j) {
        a0[i][j] += p0[i] * w0[j];
        a1[i][j] += p1[i] * w1[j];
        a2[i][j] += p2[i] * w2[j];
      }
  }
  float* dst = (mm == 0) ? dst0 : dst1;
#pragma unroll
  for (int i = 0; i < 4; ++i)
#pragma unroll
    for (int j = 0; j < 4; ++j) {
      float bc = bconv[cg * 4 + j];
      float z = tanhf(a0[i][j] + bc) + tanhf(a1[i][j] + a2[i][j] + bc);
      size_t idx = (size_t)(n0 + rg * 4 + i) * 64 + cg * 4 + j;
      dst[idx] = z;
      if (mm == 1 && extra1) extra1[idx] = z;
    }
}

extern "C" void kernel_launch(void* const* d_in, const int* in_sizes, int n_in,
                              void* d_out, int out_size, void* d_ws, size_t ws_size,
                              hipStream_t stream)
{
  const float* observation   = (const float*)d_in[0];
  const float* time_features = (const float*)d_in[1];
  const float* layer_initial = (const float*)d_in[2];
  const float* sW1   = (const float*)d_in[3];
  const float* sb1   = (const float*)d_in[4];
  const float* s_ln_g = (const float*)d_in[5];
  const float* s_ln_b = (const float*)d_in[6];
  const float* sW2   = (const float*)d_in[7];
  const float* sb2   = (const float*)d_in[8];
  const float* tW1   = (const float*)d_in[9];
  const float* tb1   = (const float*)d_in[10];
  const float* t_ln_g = (const float*)d_in[11];
  const float* t_ln_b = (const float*)d_in[12];
  const float* tW2   = (const float*)d_in[13];
  const float* tb2   = (const float*)d_in[14];
  const float* Bmat  = (const float*)d_in[15];
  const float* fW1   = (const float*)d_in[16];
  const float* fb1   = (const float*)d_in[17];
  const float* f1g   = (const float*)d_in[18];
  const float* f1b   = (const float*)d_in[19];
  const float* fW2   = (const float*)d_in[20];
  const float* fb2   = (const float*)d_in[21];
  const float* f2g   = (const float*)d_in[22];
  const float* f2b   = (const float*)d_in[23];
  const float* fW3   = (const float*)d_in[24];
  const float* fb3   = (const float*)d_in[25];
  const float* Wf    = (const float*)d_in[26];
  const float* Wb    = (const float*)d_in[27];
  const float* bconv = (const float*)d_in[28];
  float* out = (float*)d_out;

  float* ws   = (float*)d_ws;
  float* Hs   = ws;                 // 16384
  float* Ht   = Hs   + 16384;       // 16384
  float* Vs   = Ht   + 16384;       // 262144
  float* obs4 = Vs   + 262144;      // 16384
  float* part = obs4 + 16384;       // 65536
  float* h1   = part + 65536;       // 4096
  float* h2   = h1   + 4096;        // 2048
  float* Xr   = h2   + 2048;        // 262144
  float* Pm   = Xr   + 262144;      // 589824 (9 x 65536)
  float* Z1   = Pm   + 589824;      // 131072 (2 x 65536)

  head_mlp_t<1024><<<64, 256, 0, stream>>>(layer_initial, sW1, sb1, s_ln_g, s_ln_b, Hs);
  head_mlp_t<8><<<64, 256, 0, stream>>>(time_features, tW1, tb1, t_ln_g, t_ln_b, Ht);
  emb_sel<<<1024, 256, 0, stream>>>(Hs, Ht, sW2, sb2, tW2, tb2, Vs);

  obs_sel<<<64, 256, 0, stream>>>(observation, obs4);
  skinny_part<<<64, 256, 0, stream>>>(obs4, fW1, part, 4096, 1024);   // 16 kc x 4 jb
  reduce_ln_relu<1024, 16><<<4, 256, 0, stream>>>(part, fb1, f1g, f1b, h1);
  skinny_part<<<8, 256, 0, stream>>>(h1, fW2, part, 1024, 512);       // 4 kc x 2 jb
  reduce_ln_relu<512, 4><<<4, 256, 0, stream>>>(part, fb2, f2g, f2b, h2);
  big_w3<<<256, 256, 0, stream>>>(h2, fW3, fb3, Xr);

  // layer-1, m=30 (cols 60/61, X rows 0/1) and m=31 (cols 62/63, X rows 2/3)
  Pairs pA;
  pA.a[0]=1; pA.b[0]=1; pA.t[0]=1;   // k=0, m=30: A(61,61) @ X[61]
  pA.a[1]=0; pA.b[1]=1; pA.t[1]=0;   // k=1, m=30: A(60,61) @ X[60]
  pA.a[2]=1; pA.b[2]=0; pA.t[2]=0;   // k=1, m=30: A(61,60) @ X[60]
  pA.a[3]=3; pA.b[3]=3; pA.t[3]=3;   // k=0, m=31: A(63,63) @ X[63]
  pA.a[4]=2; pA.b[4]=3; pA.t[4]=2;   // k=1, m=31: A(62,63) @ X[62]
  pA.a[5]=3; pA.b[5]=2; pA.t[5]=2;   // k=1, m=31: A(63,62) @ X[62]
  attn_pair<<<96, 256, 0, stream>>>(Vs, Bmat, Xr, Pm, pA);
  combine_z<<<32, 256, 0, stream>>>(Pm, Wf, Wb, bconv, Z1, Z1 + 65536, out);

  // layer-2, m=15: cols 62(=2)/60(=0), X = Z1 rows {0: m30, 1: m31}
  Pairs pB;
  pB.a[0]=2; pB.b[0]=2; pB.t[0]=1;   // k=0: A(62,62) @ X1[31]
  pB.a[1]=0; pB.b[1]=2; pB.t[1]=0;   // k=1: A(60,62) @ X1[30]
  pB.a[2]=2; pB.b[2]=0; pB.t[2]=0;   // k=1: A(62,60) @ X1[30]
  pB.a[3]=pB.a[4]=pB.a[5]=0; pB.b[3]=pB.b[4]=pB.b[5]=0; pB.t[3]=pB.t[4]=pB.t[5]=0;
  attn_pair<<<48, 256, 0, stream>>>(Vs, Bmat, Z1, Pm + 6 * 65536, pB);
  combine_z<<<16, 256, 0, stream>>>(Pm + 6 * 65536, Wf, Wb, bconv,
                                    out + 65536, out + 65536, nullptr);
}

// Round 4
// 487.222 us; speedup vs baseline: 7.7098x; 2.2960x over previous
//
#include <hip/hip_runtime.h>
#include <cstddef>

#define EPS_C   1e-5f
#define DELTA_C 0.05f

struct Pairs { int a[6]; int b[6]; int t[6]; };

// ---------- H = relu(LN(A @ W1 + b1)) ; A:(64,K), W1:(K,256), H:(64,256) ----------
template<int K>
__global__ __launch_bounds__(256) void head_mlp_t(
    const float* __restrict__ A, const float* __restrict__ W1,
    const float* __restrict__ b1, const float* __restrict__ g,
    const float* __restrict__ bb, float* __restrict__ H)
{
  int row = blockIdx.x, j = threadIdx.x;
  __shared__ float As[K];
  for (int i = j; i < K; i += 256) As[i] = A[row * K + i];
  __syncthreads();

  float a0 = 0.f, a1 = 0.f, a2 = 0.f, a3 = 0.f;
  const float* __restrict__ Wp = W1 + j;
#pragma unroll 2
  for (int c = 0; c < K; c += 8) {
    float w0 = Wp[(size_t)(c + 0) * 256];
    float w1 = Wp[(size_t)(c + 1) * 256];
    float w2 = Wp[(size_t)(c + 2) * 256];
    float w3 = Wp[(size_t)(c + 3) * 256];
    float w4 = Wp[(size_t)(c + 4) * 256];
    float w5 = Wp[(size_t)(c + 5) * 256];
    float w6 = Wp[(size_t)(c + 6) * 256];
    float w7 = Wp[(size_t)(c + 7) * 256];
    a0 += As[c + 0] * w0 + As[c + 4] * w4;
    a1 += As[c + 1] * w1 + As[c + 5] * w5;
    a2 += As[c + 2] * w2 + As[c + 6] * w6;
    a3 += As[c + 3] * w3 + As[c + 7] * w7;
  }
  float acc = ((a0 + a1) + (a2 + a3)) + b1[j];

  __shared__ float rs[256], rs2[256];
  rs[j] = acc; rs2[j] = acc * acc;
  __syncthreads();
  for (int st = 128; st > 0; st >>= 1) {
    if (j < st) { rs[j] += rs[j + st]; rs2[j] += rs2[j + st]; }
    __syncthreads();
  }
  float mu  = rs[0] * (1.f / 256.f);
  float var = rs2[0] * (1.f / 256.f) - mu * mu;
  float y = (acc - mu) * rsqrtf(var + EPS_C) * g[j] + bb[j];
  H[row * 256 + j] = fmaxf(y, 0.f);
}

// ---------- Vs[c][n*64+l] = emb[l][n*64+60+c], c=0..3 ----------
__global__ __launch_bounds__(256) void emb_sel(
    const float* __restrict__ Hs, const float* __restrict__ Ht,
    const float* __restrict__ sW2, const float* __restrict__ sb2,
    const float* __restrict__ tW2, const float* __restrict__ tb2,
    float* __restrict__ Vs)
{
  int n = blockIdx.x, tid = threadIdx.x;
  int l = tid >> 2, c = tid & 3;
  __shared__ float wS[256][4], wT[256][4];
  {
    size_t base = (size_t)tid * 65536 + (size_t)n * 64 + 60;
    float4 a = *(const float4*)&sW2[base];
    float4 t4 = *(const float4*)&tW2[base];
    wS[tid][0] = a.x;  wS[tid][1] = a.y;  wS[tid][2] = a.z;  wS[tid][3] = a.w;
    wT[tid][0] = t4.x; wT[tid][1] = t4.y; wT[tid][2] = t4.z; wT[tid][3] = t4.w;
  }
  __syncthreads();
  const float* __restrict__ hs = Hs + l * 256;
  const float* __restrict__ ht = Ht + l * 256;
  float acc = 0.f;
  for (int k = 0; k < 256; k += 8) {
#pragma unroll
    for (int u = 0; u < 8; ++u)
      acc += hs[k + u] * wS[k + u][c] + ht[k + u] * wT[k + u][c];
  }
  int jj = n * 64 + 60 + c;
  Vs[(size_t)c * 65536 + (size_t)n * 64 + l] = acc + sb2[jj] + tb2[jj];
}

// ---------- obs4[c][n*4+df] = observation[n][df][60+c] ----------
__global__ __launch_bounds__(256) void obs_sel(
    const float* __restrict__ obs, float* __restrict__ obs4)
{
  int idx = blockIdx.x * 256 + threadIdx.x;   // 16384 total
  int c = idx >> 12;
  int r = idx & 4095;
  int n = r >> 2, df = r & 3;
  obs4[idx] = obs[n * 256 + df * 64 + 60 + c];
}

// ---------- part[(kc*4+c)*N + j] = sum_{k in chunk of 256} A[c][k0+k] * W[k0+k][j] ----------
__global__ __launch_bounds__(256) void skinny_part(
    const float* __restrict__ A, const float* __restrict__ W,
    float* __restrict__ part, int K, int N)
{
  int jblocks = N >> 8;
  int jb = blockIdx.x % jblocks;
  int kc = blockIdx.x / jblocks;
  int k0 = kc << 8;
  int tid = threadIdx.x;
  int j = (jb << 8) + tid;
  __shared__ float ARs[4][256];
#pragma unroll
  for (int c = 0; c < 4; ++c) ARs[c][tid] = A[c * K + k0 + tid];
  __syncthreads();
  float acc0 = 0.f, acc1 = 0.f, acc2 = 0.f, acc3 = 0.f;
  for (int kk = 0; kk < 256; kk += 8) {
    float w[8];
#pragma unroll
    for (int u = 0; u < 8; ++u) w[u] = W[(size_t)(k0 + kk + u) * N + j];
#pragma unroll
    for (int u = 0; u < 8; ++u) {
      acc0 += ARs[0][kk + u] * w[u];
      acc1 += ARs[1][kk + u] * w[u];
      acc2 += ARs[2][kk + u] * w[u];
      acc3 += ARs[3][kk + u] * w[u];
    }
  }
  part[(size_t)(kc * 4 + 0) * N + j] = acc0;
  part[(size_t)(kc * 4 + 1) * N + j] = acc1;
  part[(size_t)(kc * 4 + 2) * N + j] = acc2;
  part[(size_t)(kc * 4 + 3) * N + j] = acc3;
}

// ---------- out[c][j] = relu(LN(sum_parts + bias)) ; one block per row c ----------
template<int N_, int PARTS>
__global__ __launch_bounds__(256) void reduce_ln_relu(
    const float* __restrict__ part, const float* __restrict__ bias,
    const float* __restrict__ g, const float* __restrict__ bb,
    float* __restrict__ out)
{
  constexpr int PER = N_ >> 8;
  int c = blockIdx.x, tid = threadIdx.x;
  float x[PER];
  float s = 0.f, s2 = 0.f;
#pragma unroll
  for (int i = 0; i < PER; ++i) {
    int j = (i << 8) + tid;
    float v = bias[j];
#pragma unroll
    for (int p = 0; p < PARTS; ++p) v += part[(size_t)(p * 4 + c) * N_ + j];
    x[i] = v; s += v; s2 += v * v;
  }
  __shared__ float rs[256], rs2[256];
  rs[tid] = s; rs2[tid] = s2;
  __syncthreads();
  for (int st = 128; st > 0; st >>= 1) {
    if (tid < st) { rs[tid] += rs[tid + st]; rs2[tid] += rs2[tid + st]; }
    __syncthreads();
  }
  float mu  = rs[0] / (float)N_;
  float var = rs2[0] / (float)N_ - mu * mu;
  float inv = rsqrtf(var + EPS_C);
#pragma unroll
  for (int i = 0; i < PER; ++i) {
    int j = (i << 8) + tid;
    out[c * N_ + j] = fmaxf((x[i] - mu) * inv * g[j] + bb[j], 0.f);
  }
}

// ---------- Xr[c][j] = sum_k h2[c][k]*fW3[k][j] + fb3[j] ----------
__global__ __launch_bounds__(256) void big_w3(
    const float* __restrict__ h2, const float* __restrict__ fW3,
    const float* __restrict__ fb3, float* __restrict__ Xr)
{
  int tid = threadIdx.x;
  __shared__ float h2s[2048];
  for (int i = tid; i < 2048; i += 256) h2s[i] = h2[i];
  __syncthreads();
  int j = blockIdx.x * 256 + tid;
  float acc0 = 0.f, acc1 = 0.f, acc2 = 0.f, acc3 = 0.f;
  for (int k0 = 0; k0 < 512; k0 += 16) {
    float w[16];
#pragma unroll
    for (int u = 0; u < 16; ++u) w[u] = fW3[(size_t)(k0 + u) * 65536 + j];
#pragma unroll
    for (int u = 0; u < 16; ++u) {
      acc0 += h2s[k0 + u]        * w[u];
      acc1 += h2s[512 + k0 + u]  * w[u];
      acc2 += h2s[1024 + k0 + u] * w[u];
      acc3 += h2s[1536 + k0 + u] * w[u];
    }
  }
  float b = fb3[j];
  Xr[j]           = acc0 + b;
  Xr[65536 + j]   = acc1 + b;
  Xr[131072 + j]  = acc2 + b;
  Xr[196608 + j]  = acc3 + b;
}

// ---------- one attention pair: P = softmaxrow(thresh((V[a]@B)@V[b]^T)) @ X[t] ----------
__global__ __launch_bounds__(256) void attn_pair(
    const float* __restrict__ Vs, const float* __restrict__ Bmat,
    const float* __restrict__ Xbase, float* __restrict__ Pout, Pairs pr)
{
  int pi = blockIdx.x >> 4;
  int n0 = (blockIdx.x & 15) << 6;
  int tid = threadIdx.x;
  int rg = tid >> 4, cg = tid & 15;
  int a = pr.a[pi], b = pr.b[pi], t = pr.t[pi];

  __shared__ float Va[64][65];
  __shared__ float Qb[64][65];
  __shared__ float St[64][65];
  __shared__ float rowm[64], rowl[64], rowsc[64];

  for (int i = tid; i < 4096; i += 256) {
    int rr = i >> 6, cc = i & 63;
    Va[rr][cc] = Vs[(size_t)a * 65536 + (size_t)(n0 + rr) * 64 + cc];
    Qb[rr][cc] = Bmat[i];
  }
  if (tid < 64) { rowm[tid] = -1e30f; rowl[tid] = 0.f; }
  __syncthreads();

  // VaB = Va @ B
  float vb[4][4];
#pragma unroll
  for (int i = 0; i < 4; ++i)
#pragma unroll
    for (int j = 0; j < 4; ++j) vb[i][j] = 0.f;
#pragma unroll 4
  for (int l = 0; l < 64; ++l) {
    float av[4], bv[4];
#pragma unroll
    for (int i = 0; i < 4; ++i) av[i] = Va[rg * 4 + i][l];
#pragma unroll
    for (int j = 0; j < 4; ++j) bv[j] = Qb[l][cg * 4 + j];
#pragma unroll
    for (int i = 0; i < 4; ++i)
#pragma unroll
      for (int j = 0; j < 4; ++j) vb[i][j] += av[i] * bv[j];
  }
  __syncthreads();
#pragma unroll
  for (int i = 0; i < 4; ++i)
#pragma unroll
    for (int j = 0; j < 4; ++j) Va[rg * 4 + i][cg * 4 + j] = vb[i][j];
  __syncthreads();

  float P[4][4];
#pragma unroll
  for (int i = 0; i < 4; ++i)
#pragma unroll
    for (int j = 0; j < 4; ++j) P[i][j] = 0.f;

  for (int q0 = 0; q0 < 1024; q0 += 64) {
    for (int i = tid; i < 4096; i += 256) {
      int rr = i >> 6, cc = i & 63;
      Qb[rr][cc] = Vs[(size_t)b * 65536 + (size_t)(q0 + rr) * 64 + cc];
    }
    __syncthreads();
    // S tile + threshold
    float sa[4][4];
#pragma unroll
    for (int i = 0; i < 4; ++i)
#pragma unroll
      for (int j = 0; j < 4; ++j) sa[i][j] = 0.f;
#pragma unroll 4
    for (int p = 0; p < 64; ++p) {
      float av[4], qv[4];
#pragma unroll
      for (int i = 0; i < 4; ++i) av[i] = Va[rg * 4 + i][p];
#pragma unroll
      for (int j = 0; j < 4; ++j) qv[j] = Qb[cg * 4 + j][p];
#pragma unroll
      for (int i = 0; i < 4; ++i)
#pragma unroll
        for (int j = 0; j < 4; ++j) sa[i][j] += av[i] * qv[j];
    }
#pragma unroll
    for (int i = 0; i < 4; ++i)
#pragma unroll
      for (int j = 0; j < 4; ++j) {
        float sv = sa[i][j];
        St[rg * 4 + i][cg * 4 + j] = (sv >= DELTA_C) ? sv : 0.f;
      }
    __syncthreads();
    // wave-parallel online softmax: 4 lanes per row
    {
      int r = tid >> 2, sub = tid & 3;
      float tm = -1e30f;
#pragma unroll
      for (int jj = 0; jj < 16; ++jj) tm = fmaxf(tm, St[r][sub * 16 + jj]);
      tm = fmaxf(tm, __shfl_xor(tm, 1));
      tm = fmaxf(tm, __shfl_xor(tm, 2));
      float mold = rowm[r];
      float mnew = fmaxf(mold, tm);
      float ssum = 0.f;
#pragma unroll
      for (int jj = 0; jj < 16; ++jj) {
        float e = __expf(St[r][sub * 16 + jj] - mnew);
        St[r][sub * 16 + jj] = e;
        ssum += e;
      }
      ssum += __shfl_xor(ssum, 1);
      ssum += __shfl_xor(ssum, 2);
      if (sub == 0) {
        float sc = __expf(mold - mnew);
        rowsc[r] = sc;
        rowl[r] = rowl[r] * sc + ssum;
        rowm[r] = mnew;
      }
    }
    // X tile
    for (int i = tid; i < 4096; i += 256) {
      int rr = i >> 6, cc = i & 63;
      Qb[rr][cc] = Xbase[(size_t)t * 65536 + (size_t)(q0 + rr) * 64 + cc];
    }
    __syncthreads();
    float scv[4];
#pragma unroll
    for (int i = 0; i < 4; ++i) scv[i] = rowsc[rg * 4 + i];
#pragma unroll
    for (int i = 0; i < 4; ++i)
#pragma unroll
      for (int j = 0; j < 4; ++j) P[i][j] *= scv[i];
#pragma unroll 4
    for (int q = 0; q < 64; ++q) {
      float ev[4], xv[4];
#pragma unroll
      for (int i = 0; i < 4; ++i) ev[i] = St[rg * 4 + i][q];
#pragma unroll
      for (int j = 0; j < 4; ++j) xv[j] = Qb[q][cg * 4 + j];
#pragma unroll
      for (int i = 0; i < 4; ++i)
#pragma unroll
        for (int j = 0; j < 4; ++j) P[i][j] += ev[i] * xv[j];
    }
    __syncthreads();
  }
  float invl[4];
#pragma unroll
  for (int i = 0; i < 4; ++i) invl[i] = 1.f / rowl[rg * 4 + i];
#pragma unroll
  for (int i = 0; i < 4; ++i)
#pragma unroll
    for (int j = 0; j < 4; ++j)
      Pout[(size_t)pi * 65536 + (size_t)(n0 + rg * 4 + i) * 64 + cg * 4 + j] =
          P[i][j] * invl[i];
}

// ---------- Z[mm] = tanh(P0@(Wf0+Wb0)+b) + tanh(P1@Wf1 + P2@Wb1 + b) ----------
// Sequential 3-pass accumulation: low register pressure, no spills.
__global__ __launch_bounds__(256) void combine_z(
    const float* __restrict__ Pm, const float* __restrict__ Wf,
    const float* __restrict__ Wb, const float* __restrict__ bconv,
    float* __restrict__ dst0, float* __restrict__ dst1, float* __restrict__ extra1)
{
  int mm = blockIdx.x >> 4;
  int n0 = (blockIdx.x & 15) << 6;
  int tid = threadIdx.x;
  int rg = tid >> 4, cg = tid & 15;
  __shared__ float Wt[64][65];
  __shared__ float Pt[64][65];

  float a0[4][4], a1[4][4];
#pragma unroll
  for (int i = 0; i < 4; ++i)
#pragma unroll
    for (int j = 0; j < 4; ++j) { a0[i][j] = 0.f; a1[i][j] = 0.f; }

  for (int pass = 0; pass < 3; ++pass) {
    __syncthreads();
    for (int i = tid; i < 4096; i += 256) {
      int rr = i >> 6, cc = i & 63;
      float w;
      if (pass == 0)      w = Wf[i] + Wb[i];
      else if (pass == 1) w = Wf[4096 + i];
      else                w = Wb[4096 + i];
      Wt[rr][cc] = w;
      Pt[rr][cc] = Pm[(size_t)(3 * mm + pass) * 65536 + (size_t)n0 * 64 + i];
    }
    __syncthreads();
    float acc[4][4];
#pragma unroll
    for (int i = 0; i < 4; ++i)
#pragma unroll
      for (int j = 0; j < 4; ++j) acc[i][j] = 0.f;
#pragma unroll 4
    for (int ff = 0; ff < 64; ++ff) {
      float p[4], w[4];
#pragma unroll
      for (int i = 0; i < 4; ++i) p[i] = Pt[rg * 4 + i][ff];
#pragma unroll
      for (int j = 0; j < 4; ++j) w[j] = Wt[ff][cg * 4 + j];
#pragma unroll
      for (int i = 0; i < 4; ++i)
#pragma unroll
        for (int j = 0; j < 4; ++j) acc[i][j] += p[i] * w[j];
    }
    if (pass == 0) {
#pragma unroll
      for (int i = 0; i < 4; ++i)
#pragma unroll
        for (int j = 0; j < 4; ++j) a0[i][j] = acc[i][j];
    } else {
#pragma unroll
      for (int i = 0; i < 4; ++i)
#pragma unroll
        for (int j = 0; j < 4; ++j) a1[i][j] += acc[i][j];
    }
  }

  float* dst = (mm == 0) ? dst0 : dst1;
#pragma unroll
  for (int i = 0; i < 4; ++i)
#pragma unroll
    for (int j = 0; j < 4; ++j) {
      float bc = bconv[cg * 4 + j];
      float z = tanhf(a0[i][j] + bc) + tanhf(a1[i][j] + bc);
      size_t idx = (size_t)(n0 + rg * 4 + i) * 64 + cg * 4 + j;
      dst[idx] = z;
      if (mm == 1 && extra1) extra1[idx] = z;
    }
}

extern "C" void kernel_launch(void* const* d_in, const int* in_sizes, int n_in,
                              void* d_out, int out_size, void* d_ws, size_t ws_size,
                              hipStream_t stream)
{
  const float* observation   = (const float*)d_in[0];
  const float* time_features = (const float*)d_in[1];
  const float* layer_initial = (const float*)d_in[2];
  const float* sW1   = (const float*)d_in[3];
  const float* sb1   = (const float*)d_in[4];
  const float* s_ln_g = (const float*)d_in[5];
  const float* s_ln_b = (const float*)d_in[6];
  const float* sW2   = (const float*)d_in[7];
  const float* sb2   = (const float*)d_in[8];
  const float* tW1   = (const float*)d_in[9];
  const float* tb1   = (const float*)d_in[10];
  const float* t_ln_g = (const float*)d_in[11];
  const float* t_ln_b = (const float*)d_in[12];
  const float* tW2   = (const float*)d_in[13];
  const float* tb2   = (const float*)d_in[14];
  const float* Bmat  = (const float*)d_in[15];
  const float* fW1   = (const float*)d_in[16];
  const float* fb1   = (const float*)d_in[17];
  const float* f1g   = (const float*)d_in[18];
  const float* f1b   = (const float*)d_in[19];
  const float* fW2   = (const float*)d_in[20];
  const float* fb2   = (const float*)d_in[21];
  const float* f2g   = (const float*)d_in[22];
  const float* f2b   = (const float*)d_in[23];
  const float* fW3   = (const float*)d_in[24];
  const float* fb3   = (const float*)d_in[25];
  const float* Wf    = (const float*)d_in[26];
  const float* Wb    = (const float*)d_in[27];
  const float* bconv = (const float*)d_in[28];
  float* out = (float*)d_out;

  float* ws   = (float*)d_ws;
  float* Hs   = ws;                 // 16384
  float* Ht   = Hs   + 16384;       // 16384
  float* Vs   = Ht   + 16384;       // 262144
  float* obs4 = Vs   + 262144;      // 16384
  float* part = obs4 + 16384;       // 65536
  float* h1   = part + 65536;       // 4096
  float* h2   = h1   + 4096;        // 2048
  float* Xr   = h2   + 2048;        // 262144
  float* Pm   = Xr   + 262144;      // 589824 (9 x 65536)
  float* Z1   = Pm   + 589824;      // 131072 (2 x 65536)

  head_mlp_t<1024><<<64, 256, 0, stream>>>(layer_initial, sW1, sb1, s_ln_g, s_ln_b, Hs);
  head_mlp_t<8><<<64, 256, 0, stream>>>(time_features, tW1, tb1, t_ln_g, t_ln_b, Ht);
  emb_sel<<<1024, 256, 0, stream>>>(Hs, Ht, sW2, sb2, tW2, tb2, Vs);

  obs_sel<<<64, 256, 0, stream>>>(observation, obs4);
  skinny_part<<<64, 256, 0, stream>>>(obs4, fW1, part, 4096, 1024);   // 16 kc x 4 jb
  reduce_ln_relu<1024, 16><<<4, 256, 0, stream>>>(part, fb1, f1g, f1b, h1);
  skinny_part<<<8, 256, 0, stream>>>(h1, fW2, part, 1024, 512);       // 4 kc x 2 jb
  reduce_ln_relu<512, 4><<<4, 256, 0, stream>>>(part, fb2, f2g, f2b, h2);
  big_w3<<<256, 256, 0, stream>>>(h2, fW3, fb3, Xr);

  // layer-1, m=30 (cols 60/61, X rows 0/1) and m=31 (cols 62/63, X rows 2/3)
  Pairs pA;
  pA.a[0]=1; pA.b[0]=1; pA.t[0]=1;   // k=0, m=30: A(61,61) @ X[61]
  pA.a[1]=0; pA.b[1]=1; pA.t[1]=0;   // k=1, m=30: A(60,61) @ X[60]
  pA.a[2]=1; pA.b[2]=0; pA.t[2]=0;   // k=1, m=30: A(61,60) @ X[60]
  pA.a[3]=3; pA.b[3]=3; pA.t[3]=3;   // k=0, m=31: A(63,63) @ X[63]
  pA.a[4]=2; pA.b[4]=3; pA.t[4]=2;   // k=1, m=31: A(62,63) @ X[62]
  pA.a[5]=3; pA.b[5]=2; pA.t[5]=2;   // k=1, m=31: A(63,62) @ X[62]
  attn_pair<<<96, 256, 0, stream>>>(Vs, Bmat, Xr, Pm, pA);
  combine_z<<<32, 256, 0, stream>>>(Pm, Wf, Wb, bconv, Z1, Z1 + 65536, out);

  // layer-2, m=15: cols 62(=2)/60(=0), X = Z1 rows {0: m30, 1: m31}
  Pairs pB;
  pB.a[0]=2; pB.b[0]=2; pB.t[0]=1;   // k=0: A(62,62) @ X1[31]
  pB.a[1]=0; pB.b[1]=2; pB.t[1]=0;   // k=1: A(60,62) @ X1[30]
  pB.a[2]=2; pB.b[2]=0; pB.t[2]=0;   // k=1: A(62,60) @ X1[30]
  pB.a[3]=pB.a[4]=pB.a[5]=0; pB.b[3]=pB.b[4]=pB.b[5]=0; pB.t[3]=pB.t[4]=pB.t[5]=0;
  attn_pair<<<48, 256, 0, stream>>>(Vs, Bmat, Z1, Pm + 6 * 65536, pB);
  combine_z<<<16, 256, 0, stream>>>(Pm + 6 * 65536, Wf, Wb, bconv,
                                    out + 65536, out + 65536, nullptr);
}

// Round 5
// 249.168 us; speedup vs baseline: 15.0757x; 1.9554x over previous
//
#include <hip/hip_runtime.h>
#include <cstddef>

#define EPS_C   1e-5f
#define DELTA_C 0.05f
#define NS      8   // q-splits per attention instance (1024 / NS = 128 per block)

struct Pairs { int a[6]; int b[6]; int t[6]; };

// ---------- H = relu(LN(A @ W1 + b1)) ; A:(64,K), W1:(K,256), H:(64,256) ----------
template<int K>
__global__ __launch_bounds__(256) void head_mlp_t(
    const float* __restrict__ A, const float* __restrict__ W1,
    const float* __restrict__ b1, const float* __restrict__ g,
    const float* __restrict__ bb, float* __restrict__ H)
{
  int row = blockIdx.x, j = threadIdx.x;
  __shared__ float As[K];
  for (int i = j; i < K; i += 256) As[i] = A[row * K + i];
  __syncthreads();

  float a0 = 0.f, a1 = 0.f, a2 = 0.f, a3 = 0.f;
  const float* __restrict__ Wp = W1 + j;
#pragma unroll 2
  for (int c = 0; c < K; c += 8) {
    float w0 = Wp[(size_t)(c + 0) * 256];
    float w1 = Wp[(size_t)(c + 1) * 256];
    float w2 = Wp[(size_t)(c + 2) * 256];
    float w3 = Wp[(size_t)(c + 3) * 256];
    float w4 = Wp[(size_t)(c + 4) * 256];
    float w5 = Wp[(size_t)(c + 5) * 256];
    float w6 = Wp[(size_t)(c + 6) * 256];
    float w7 = Wp[(size_t)(c + 7) * 256];
    a0 += As[c + 0] * w0 + As[c + 4] * w4;
    a1 += As[c + 1] * w1 + As[c + 5] * w5;
    a2 += As[c + 2] * w2 + As[c + 6] * w6;
    a3 += As[c + 3] * w3 + As[c + 7] * w7;
  }
  float acc = ((a0 + a1) + (a2 + a3)) + b1[j];

  __shared__ float rs[256], rs2[256];
  rs[j] = acc; rs2[j] = acc * acc;
  __syncthreads();
  for (int st = 128; st > 0; st >>= 1) {
    if (j < st) { rs[j] += rs[j + st]; rs2[j] += rs2[j + st]; }
    __syncthreads();
  }
  float mu  = rs[0] * (1.f / 256.f);
  float var = rs2[0] * (1.f / 256.f) - mu * mu;
  float y = (acc - mu) * rsqrtf(var + EPS_C) * g[j] + bb[j];
  H[row * 256 + j] = fmaxf(y, 0.f);
}

// ---------- Vs[c][n*64+l] = emb[l][n*64+60+c], c=0..3 ----------
__global__ __launch_bounds__(256) void emb_sel(
    const float* __restrict__ Hs, const float* __restrict__ Ht,
    const float* __restrict__ sW2, const float* __restrict__ sb2,
    const float* __restrict__ tW2, const float* __restrict__ tb2,
    float* __restrict__ Vs)
{
  int n = blockIdx.x, tid = threadIdx.x;
  int l = tid >> 2, c = tid & 3;
  __shared__ float wS[256][4], wT[256][4];
  {
    size_t base = (size_t)tid * 65536 + (size_t)n * 64 + 60;
    float4 a = *(const float4*)&sW2[base];
    float4 t4 = *(const float4*)&tW2[base];
    wS[tid][0] = a.x;  wS[tid][1] = a.y;  wS[tid][2] = a.z;  wS[tid][3] = a.w;
    wT[tid][0] = t4.x; wT[tid][1] = t4.y; wT[tid][2] = t4.z; wT[tid][3] = t4.w;
  }
  __syncthreads();
  const float* __restrict__ hs = Hs + l * 256;
  const float* __restrict__ ht = Ht + l * 256;
  float acc = 0.f;
  for (int k = 0; k < 256; k += 8) {
#pragma unroll
    for (int u = 0; u < 8; ++u)
      acc += hs[k + u] * wS[k + u][c] + ht[k + u] * wT[k + u][c];
  }
  int jj = n * 64 + 60 + c;
  Vs[(size_t)c * 65536 + (size_t)n * 64 + l] = acc + sb2[jj] + tb2[jj];
}

// ---------- obs4[c][n*4+df] = observation[n][df][60+c] ----------
__global__ __launch_bounds__(256) void obs_sel(
    const float* __restrict__ obs, float* __restrict__ obs4)
{
  int idx = blockIdx.x * 256 + threadIdx.x;   // 16384 total
  int c = idx >> 12;
  int r = idx & 4095;
  int n = r >> 2, df = r & 3;
  obs4[idx] = obs[n * 256 + df * 64 + 60 + c];
}

// ---------- part[(kc*4+c)*N + j] = partial skinny GEMM over a 256-k chunk ----------
__global__ __launch_bounds__(256) void skinny_part(
    const float* __restrict__ A, const float* __restrict__ W,
    float* __restrict__ part, int K, int N)
{
  int jblocks = N >> 8;
  int jb = blockIdx.x % jblocks;
  int kc = blockIdx.x / jblocks;
  int k0 = kc << 8;
  int tid = threadIdx.x;
  int j = (jb << 8) + tid;
  __shared__ float ARs[4][256];
#pragma unroll
  for (int c = 0; c < 4; ++c) ARs[c][tid] = A[c * K + k0 + tid];
  __syncthreads();
  float acc0 = 0.f, acc1 = 0.f, acc2 = 0.f, acc3 = 0.f;
  for (int kk = 0; kk < 256; kk += 8) {
    float w[8];
#pragma unroll
    for (int u = 0; u < 8; ++u) w[u] = W[(size_t)(k0 + kk + u) * N + j];
#pragma unroll
    for (int u = 0; u < 8; ++u) {
      acc0 += ARs[0][kk + u] * w[u];
      acc1 += ARs[1][kk + u] * w[u];
      acc2 += ARs[2][kk + u] * w[u];
      acc3 += ARs[3][kk + u] * w[u];
    }
  }
  part[(size_t)(kc * 4 + 0) * N + j] = acc0;
  part[(size_t)(kc * 4 + 1) * N + j] = acc1;
  part[(size_t)(kc * 4 + 2) * N + j] = acc2;
  part[(size_t)(kc * 4 + 3) * N + j] = acc3;
}

// ---------- out[c][j] = relu(LN(sum_parts + bias)) ----------
template<int N_, int PARTS>
__global__ __launch_bounds__(256) void reduce_ln_relu(
    const float* __restrict__ part, const float* __restrict__ bias,
    const float* __restrict__ g, const float* __restrict__ bb,
    float* __restrict__ out)
{
  constexpr int PER = N_ >> 8;
  int c = blockIdx.x, tid = threadIdx.x;
  float x[PER];
  float s = 0.f, s2 = 0.f;
#pragma unroll
  for (int i = 0; i < PER; ++i) {
    int j = (i << 8) + tid;
    float v = bias[j];
#pragma unroll
    for (int p = 0; p < PARTS; ++p) v += part[(size_t)(p * 4 + c) * N_ + j];
    x[i] = v; s += v; s2 += v * v;
  }
  __shared__ float rs[256], rs2[256];
  rs[tid] = s; rs2[tid] = s2;
  __syncthreads();
  for (int st = 128; st > 0; st >>= 1) {
    if (tid < st) { rs[tid] += rs[tid + st]; rs2[tid] += rs2[tid + st]; }
    __syncthreads();
  }
  float mu  = rs[0] / (float)N_;
  float var = rs2[0] / (float)N_ - mu * mu;
  float inv = rsqrtf(var + EPS_C);
#pragma unroll
  for (int i = 0; i < PER; ++i) {
    int j = (i << 8) + tid;
    out[c * N_ + j] = fmaxf((x[i] - mu) * inv * g[j] + bb[j], 0.f);
  }
}

// ---------- Xr[c][j] = sum_k h2[c][k]*fW3[k][j] + fb3[j] ----------
__global__ __launch_bounds__(256) void big_w3(
    const float* __restrict__ h2, const float* __restrict__ fW3,
    const float* __restrict__ fb3, float* __restrict__ Xr)
{
  int tid = threadIdx.x;
  __shared__ float h2s[2048];
  for (int i = tid; i < 2048; i += 256) h2s[i] = h2[i];
  __syncthreads();
  int j = blockIdx.x * 256 + tid;
  float acc0 = 0.f, acc1 = 0.f, acc2 = 0.f, acc3 = 0.f;
  for (int k0 = 0; k0 < 512; k0 += 16) {
    float w[16];
#pragma unroll
    for (int u = 0; u < 16; ++u) w[u] = fW3[(size_t)(k0 + u) * 65536 + j];
#pragma unroll
    for (int u = 0; u < 16; ++u) {
      acc0 += h2s[k0 + u]        * w[u];
      acc1 += h2s[512 + k0 + u]  * w[u];
      acc2 += h2s[1024 + k0 + u] * w[u];
      acc3 += h2s[1536 + k0 + u] * w[u];
    }
  }
  float b = fb3[j];
  Xr[j]           = acc0 + b;
  Xr[65536 + j]   = acc1 + b;
  Xr[131072 + j]  = acc2 + b;
  Xr[196608 + j]  = acc3 + b;
}

// ---------- VaB[c] = Vs[c] @ B  (per 64-row tile) ----------
__global__ __launch_bounds__(256) void vab_k(
    const float* __restrict__ Vs, const float* __restrict__ Bmat,
    float* __restrict__ VaBg)
{
  int c = blockIdx.x >> 4, nb = blockIdx.x & 15;
  int n0 = nb << 6, tid = threadIdx.x;
  int rg = tid >> 4, cg = tid & 15;
  __shared__ float Va[64][65], Bs[64][65];
#pragma unroll
  for (int i = 0; i < 4; ++i) {
    int flat = i * 1024 + tid * 4;
    int rr = flat >> 6, cc = flat & 63;
    float4 v = *(const float4*)&Vs[(size_t)c * 65536 + (size_t)(n0 + rr) * 64 + cc];
    Va[rr][cc] = v.x; Va[rr][cc+1] = v.y; Va[rr][cc+2] = v.z; Va[rr][cc+3] = v.w;
    float4 w = *(const float4*)&Bmat[flat];
    Bs[rr][cc] = w.x; Bs[rr][cc+1] = w.y; Bs[rr][cc+2] = w.z; Bs[rr][cc+3] = w.w;
  }
  __syncthreads();
  float acc[4][4];
#pragma unroll
  for (int i = 0; i < 4; ++i)
#pragma unroll
    for (int j = 0; j < 4; ++j) acc[i][j] = 0.f;
#pragma unroll 4
  for (int l = 0; l < 64; ++l) {
    float av[4], bv[4];
#pragma unroll
    for (int i = 0; i < 4; ++i) av[i] = Va[rg * 4 + i][l];
#pragma unroll
    for (int j = 0; j < 4; ++j) bv[j] = Bs[l][cg * 4 + j];
#pragma unroll
    for (int i = 0; i < 4; ++i)
#pragma unroll
      for (int j = 0; j < 4; ++j) acc[i][j] += av[i] * bv[j];
  }
#pragma unroll
  for (int i = 0; i < 4; ++i) {
    float4 st = { acc[i][0], acc[i][1], acc[i][2], acc[i][3] };
    *(float4*)&VaBg[(size_t)c * 65536 + (size_t)(n0 + rg * 4 + i) * 64 + cg * 4] = st;
  }
}

// ---------- split-flash attention partial over a 128-wide q-chunk ----------
// grid = npairs * 16(nb) * NS(s). Writes un-normalized P + (m,l) per row.
__global__ __launch_bounds__(256) void attn_partial(
    const float* __restrict__ VaBg, const float* __restrict__ Vs,
    const float* __restrict__ Xbase, float* __restrict__ Pl,
    float* __restrict__ ml, Pairs pr, int slotBase)
{
  int pi  = blockIdx.x >> 7;      // /(16*NS)
  int rem = blockIdx.x & 127;
  int nb  = rem >> 3;
  int s   = rem & 7;
  int n0  = nb << 6;
  int tid = threadIdx.x;
  int rg = tid >> 4, cg = tid & 15;
  int a = pr.a[pi], b = pr.b[pi], t = pr.t[pi];

  __shared__ float Va[64][65];    // VaB rows
  __shared__ float Qb[64][65];    // Vb tile
  __shared__ float St[64][65];    // S -> exp tile
  __shared__ float Xs[64][65];    // X tile
  __shared__ float rowm[64], rowl[64], rowsc[64];

#pragma unroll
  for (int i = 0; i < 4; ++i) {
    int flat = i * 1024 + tid * 4;
    int rr = flat >> 6, cc = flat & 63;
    float4 v = *(const float4*)&VaBg[(size_t)a * 65536 + (size_t)(n0 + rr) * 64 + cc];
    Va[rr][cc] = v.x; Va[rr][cc+1] = v.y; Va[rr][cc+2] = v.z; Va[rr][cc+3] = v.w;
  }
  if (tid < 64) { rowm[tid] = -1e30f; rowl[tid] = 0.f; }
  __syncthreads();

  float P[4][4];
#pragma unroll
  for (int i = 0; i < 4; ++i)
#pragma unroll
    for (int j = 0; j < 4; ++j) P[i][j] = 0.f;

  for (int ti = 0; ti < 2; ++ti) {
    int q0 = (s << 7) + (ti << 6);
    if (ti) __syncthreads();   // protect Qb/Xs/St from previous tile readers
#pragma unroll
    for (int i = 0; i < 4; ++i) {
      int flat = i * 1024 + tid * 4;
      int rr = flat >> 6, cc = flat & 63;
      float4 v = *(const float4*)&Vs[(size_t)b * 65536 + (size_t)(q0 + rr) * 64 + cc];
      Qb[rr][cc] = v.x; Qb[rr][cc+1] = v.y; Qb[rr][cc+2] = v.z; Qb[rr][cc+3] = v.w;
      float4 x = *(const float4*)&Xbase[(size_t)t * 65536 + (size_t)(q0 + rr) * 64 + cc];
      Xs[rr][cc] = x.x; Xs[rr][cc+1] = x.y; Xs[rr][cc+2] = x.z; Xs[rr][cc+3] = x.w;
    }
    __syncthreads();
    // S tile + threshold
    float sa[4][4];
#pragma unroll
    for (int i = 0; i < 4; ++i)
#pragma unroll
      for (int j = 0; j < 4; ++j) sa[i][j] = 0.f;
#pragma unroll 4
    for (int p = 0; p < 64; ++p) {
      float av[4], qv[4];
#pragma unroll
      for (int i = 0; i < 4; ++i) av[i] = Va[rg * 4 + i][p];
#pragma unroll
      for (int j = 0; j < 4; ++j) qv[j] = Qb[cg * 4 + j][p];
#pragma unroll
      for (int i = 0; i < 4; ++i)
#pragma unroll
        for (int j = 0; j < 4; ++j) sa[i][j] += av[i] * qv[j];
    }
#pragma unroll
    for (int i = 0; i < 4; ++i)
#pragma unroll
      for (int j = 0; j < 4; ++j) {
        float sv = sa[i][j];
        St[rg * 4 + i][cg * 4 + j] = (sv >= DELTA_C) ? sv : 0.f;
      }
    __syncthreads();
    // wave-parallel online softmax: 4 lanes per row
    {
      int r = tid >> 2, sub = tid & 3;
      float tm = -1e30f;
#pragma unroll
      for (int jj = 0; jj < 16; ++jj) tm = fmaxf(tm, St[r][sub * 16 + jj]);
      tm = fmaxf(tm, __shfl_xor(tm, 1));
      tm = fmaxf(tm, __shfl_xor(tm, 2));
      float mold = rowm[r];
      float mnew = fmaxf(mold, tm);
      float ssum = 0.f;
#pragma unroll
      for (int jj = 0; jj < 16; ++jj) {
        float e = __expf(St[r][sub * 16 + jj] - mnew);
        St[r][sub * 16 + jj] = e;
        ssum += e;
      }
      ssum += __shfl_xor(ssum, 1);
      ssum += __shfl_xor(ssum, 2);
      if (sub == 0) {
        float sc = __expf(mold - mnew);
        rowsc[r] = sc;
        rowl[r] = rowl[r] * sc + ssum;
        rowm[r] = mnew;
      }
    }
    __syncthreads();
    // rescale + PV
    float scv[4];
#pragma unroll
    for (int i = 0; i < 4; ++i) scv[i] = rowsc[rg * 4 + i];
#pragma unroll
    for (int i = 0; i < 4; ++i)
#pragma unroll
      for (int j = 0; j < 4; ++j) P[i][j] *= scv[i];
#pragma unroll 4
    for (int q = 0; q < 64; ++q) {
      float ev[4], xv[4];
#pragma unroll
      for (int i = 0; i < 4; ++i) ev[i] = St[rg * 4 + i][q];
#pragma unroll
      for (int j = 0; j < 4; ++j) xv[j] = Xs[q][cg * 4 + j];
#pragma unroll
      for (int i = 0; i < 4; ++i)
#pragma unroll
        for (int j = 0; j < 4; ++j) P[i][j] += ev[i] * xv[j];
    }
  }
  // write un-normalized partial (rowm/rowl last written before the PV sync)
  size_t base = (size_t)((slotBase + pi) * 16 + nb) * NS + s;
  float* pp = Pl + base * 4096;
#pragma unroll
  for (int i = 0; i < 4; ++i) {
    float4 st = { P[i][0], P[i][1], P[i][2], P[i][3] };
    *(float4*)&pp[(size_t)(rg * 4 + i) * 64 + cg * 4] = st;
  }
  if (tid < 64) {
    float* mlp = ml + base * 128;
    mlp[tid]      = rowm[tid];
    mlp[64 + tid] = rowl[tid];
  }
}

// ---------- merge NS splits per instance, normalize, apply Wf/Wb + tanh ----------
// grid = n_mm * 16. Z[mm] = tanh(P0@(Wf0+Wb0)+b) + tanh(P1@Wf1 + P2@Wb1 + b)
__global__ __launch_bounds__(256) void merge_combine(
    const float* __restrict__ Pl, const float* __restrict__ ml,
    const float* __restrict__ Wf, const float* __restrict__ Wb,
    const float* __restrict__ bconv, int slotBase,
    float* __restrict__ dst0, float* __restrict__ dst1, float* __restrict__ extra1)
{
  int mm = blockIdx.x >> 4;
  int nb = blockIdx.x & 15;
  int n0 = nb << 6;
  int tid = threadIdx.x;
  int rg = tid >> 4, cg = tid & 15;
  int r  = tid >> 2, sub = tid & 3;

  __shared__ float Pt[64][65];
  __shared__ float Wt[64][65];

  float a0[4][4], a1[4][4];
#pragma unroll
  for (int i = 0; i < 4; ++i)
#pragma unroll
    for (int j = 0; j < 4; ++j) { a0[i][j] = 0.f; a1[i][j] = 0.f; }

  for (int inst = 0; inst < 3; ++inst) {
    int slot = slotBase + mm * 3 + inst;
    size_t base = (size_t)(slot * 16 + nb) * NS;
    const float* mlp = ml + base * 128;
    float mg = -1e30f;
#pragma unroll
    for (int s2 = 0; s2 < NS; ++s2) mg = fmaxf(mg, mlp[s2 * 128 + r]);
    float acc[16];
#pragma unroll
    for (int u = 0; u < 16; ++u) acc[u] = 0.f;
    float lg = 0.f;
#pragma unroll
    for (int s2 = 0; s2 < NS; ++s2) {
      float f = __expf(mlp[s2 * 128 + r] - mg);
      lg += f * mlp[s2 * 128 + 64 + r];
      const float4* ps = (const float4*)(Pl + (base + s2) * 4096 + r * 64 + sub * 16);
#pragma unroll
      for (int u = 0; u < 4; ++u) {
        float4 v = ps[u];
        acc[u*4+0] += f * v.x; acc[u*4+1] += f * v.y;
        acc[u*4+2] += f * v.z; acc[u*4+3] += f * v.w;
      }
    }
    float inv = 1.f / lg;
    if (inst) __syncthreads();   // protect Pt/Wt from previous GEMM readers
#pragma unroll
    for (int u = 0; u < 16; ++u) Pt[r][sub * 16 + u] = acc[u] * inv;
    for (int i = tid; i < 4096; i += 256) {
      int rr = i >> 6, cc = i & 63;
      float w;
      if (inst == 0)      w = Wf[i] + Wb[i];
      else if (inst == 1) w = Wf[4096 + i];
      else                w = Wb[4096 + i];
      Wt[rr][cc] = w;
    }
    __syncthreads();
    float g2[4][4];
#pragma unroll
    for (int i = 0; i < 4; ++i)
#pragma unroll
      for (int j = 0; j < 4; ++j) g2[i][j] = 0.f;
#pragma unroll 4
    for (int ff = 0; ff < 64; ++ff) {
      float p[4], w[4];
#pragma unroll
      for (int i = 0; i < 4; ++i) p[i] = Pt[rg * 4 + i][ff];
#pragma unroll
      for (int j = 0; j < 4; ++j) w[j] = Wt[ff][cg * 4 + j];
#pragma unroll
      for (int i = 0; i < 4; ++i)
#pragma unroll
        for (int j = 0; j < 4; ++j) g2[i][j] += p[i] * w[j];
    }
    if (inst == 0) {
#pragma unroll
      for (int i = 0; i < 4; ++i)
#pragma unroll
        for (int j = 0; j < 4; ++j) a0[i][j] = g2[i][j];
    } else {
#pragma unroll
      for (int i = 0; i < 4; ++i)
#pragma unroll
        for (int j = 0; j < 4; ++j) a1[i][j] += g2[i][j];
    }
  }

  float* dst = (mm == 0) ? dst0 : dst1;
#pragma unroll
  for (int i = 0; i < 4; ++i)
#pragma unroll
    for (int j = 0; j < 4; ++j) {
      float bc = bconv[cg * 4 + j];
      float z = tanhf(a0[i][j] + bc) + tanhf(a1[i][j] + bc);
      size_t idx = (size_t)(n0 + rg * 4 + i) * 64 + cg * 4 + j;
      dst[idx] = z;
      if (mm == 1 && extra1) extra1[idx] = z;
    }
}

extern "C" void kernel_launch(void* const* d_in, const int* in_sizes, int n_in,
                              void* d_out, int out_size, void* d_ws, size_t ws_size,
                              hipStream_t stream)
{
  const float* observation   = (const float*)d_in[0];
  const float* time_features = (const float*)d_in[1];
  const float* layer_initial = (const float*)d_in[2];
  const float* sW1   = (const float*)d_in[3];
  const float* sb1   = (const float*)d_in[4];
  const float* s_ln_g = (const float*)d_in[5];
  const float* s_ln_b = (const float*)d_in[6];
  const float* sW2   = (const float*)d_in[7];
  const float* sb2   = (const float*)d_in[8];
  const float* tW1   = (const float*)d_in[9];
  const float* tb1   = (const float*)d_in[10];
  const float* t_ln_g = (const float*)d_in[11];
  const float* t_ln_b = (const float*)d_in[12];
  const float* tW2   = (const float*)d_in[13];
  const float* tb2   = (const float*)d_in[14];
  const float* Bmat  = (const float*)d_in[15];
  const float* fW1   = (const float*)d_in[16];
  const float* fb1   = (const float*)d_in[17];
  const float* f1g   = (const float*)d_in[18];
  const float* f1b   = (const float*)d_in[19];
  const float* fW2   = (const float*)d_in[20];
  const float* fb2   = (const float*)d_in[21];
  const float* f2g   = (const float*)d_in[22];
  const float* f2b   = (const float*)d_in[23];
  const float* fW3   = (const float*)d_in[24];
  const float* fb3   = (const float*)d_in[25];
  const float* Wf    = (const float*)d_in[26];
  const float* Wb    = (const float*)d_in[27];
  const float* bconv = (const float*)d_in[28];
  float* out = (float*)d_out;

  float* ws   = (float*)d_ws;
  float* Hs   = ws;                 // 16384
  float* Ht   = Hs   + 16384;       // 16384
  float* Vs   = Ht   + 16384;       // 262144
  float* obs4 = Vs   + 262144;      // 16384
  float* part = obs4 + 16384;       // 65536
  float* h1   = part + 65536;       // 4096
  float* h2   = h1   + 4096;        // 2048
  float* Xr   = h2   + 2048;        // 262144
  float* VaB  = Xr   + 262144;      // 262144
  float* Pl   = VaB  + 262144;      // 9*16*NS*4096 = 4,718,592
  float* ml   = Pl   + 4718592;     // 9*16*NS*128  = 147,456
  float* Z1   = ml   + 147456;      // 131072 (2 x 65536)

  head_mlp_t<1024><<<64, 256, 0, stream>>>(layer_initial, sW1, sb1, s_ln_g, s_ln_b, Hs);
  head_mlp_t<8><<<64, 256, 0, stream>>>(time_features, tW1, tb1, t_ln_g, t_ln_b, Ht);
  emb_sel<<<1024, 256, 0, stream>>>(Hs, Ht, sW2, sb2, tW2, tb2, Vs);
  vab_k<<<64, 256, 0, stream>>>(Vs, Bmat, VaB);

  obs_sel<<<64, 256, 0, stream>>>(observation, obs4);
  skinny_part<<<64, 256, 0, stream>>>(obs4, fW1, part, 4096, 1024);   // 16 kc x 4 jb
  reduce_ln_relu<1024, 16><<<4, 256, 0, stream>>>(part, fb1, f1g, f1b, h1);
  skinny_part<<<8, 256, 0, stream>>>(h1, fW2, part, 1024, 512);       // 4 kc x 2 jb
  reduce_ln_relu<512, 4><<<4, 256, 0, stream>>>(part, fb2, f2g, f2b, h2);
  big_w3<<<256, 256, 0, stream>>>(h2, fW3, fb3, Xr);

  // layer-1, m=30 (cols 60/61, X rows 0/1) and m=31 (cols 62/63, X rows 2/3)
  Pairs pA;
  pA.a[0]=1; pA.b[0]=1; pA.t[0]=1;   // k=0, m=30: A(61,61) @ X[61]
  pA.a[1]=0; pA.b[1]=1; pA.t[1]=0;   // k=1, m=30: A(60,61) @ X[60]
  pA.a[2]=1; pA.b[2]=0; pA.t[2]=0;   // k=1, m=30: A(61,60) @ X[60]
  pA.a[3]=3; pA.b[3]=3; pA.t[3]=3;   // k=0, m=31: A(63,63) @ X[63]
  pA.a[4]=2; pA.b[4]=3; pA.t[4]=2;   // k=1, m=31: A(62,63) @ X[62]
  pA.a[5]=3; pA.b[5]=2; pA.t[5]=2;   // k=1, m=31: A(63,62) @ X[62]
  attn_partial<<<6 * 16 * NS, 256, 0, stream>>>(VaB, Vs, Xr, Pl, ml, pA, 0);
  merge_combine<<<32, 256, 0, stream>>>(Pl, ml, Wf, Wb, bconv, 0,
                                        Z1, Z1 + 65536, out);

  // layer-2, m=15: cols 62(=2)/60(=0), X = Z1 rows {0: m30, 1: m31}
  Pairs pB;
  pB.a[0]=2; pB.b[0]=2; pB.t[0]=1;   // k=0: A(62,62) @ X1[31]
  pB.a[1]=0; pB.b[1]=2; pB.t[1]=0;   // k=1: A(60,62) @ X1[30]
  pB.a[2]=2; pB.b[2]=0; pB.t[2]=0;   // k=1: A(62,60) @ X1[30]
  pB.a[3]=pB.a[4]=pB.a[5]=0; pB.b[3]=pB.b[4]=pB.b[5]=0; pB.t[3]=pB.t[4]=pB.t[5]=0;
  attn_partial<<<3 * 16 * NS, 256, 0, stream>>>(VaB, Vs, Z1, Pl, ml, pB, 6);
  merge_combine<<<16, 256, 0, stream>>>(Pl, ml, Wf, Wb, bconv, 6,
                                        out + 65536, nullptr, nullptr);
}

// Round 6
// 196.676 us; speedup vs baseline: 19.0994x; 1.2669x over previous
//
#include <hip/hip_runtime.h>
#include <cstddef>

#define EPS_C   1e-5f
#define DELTA_C 0.05f
#define NS      8   // q-splits per attention instance

struct Pairs { int a[6]; int b[6]; int t[6]; };

// ---------- H = relu(LN(A @ W1 + b1)) ; A:(64,K), W1:(K,256), H:(64,256) ----------
template<int K>
__global__ __launch_bounds__(256) void head_mlp_t(
    const float* __restrict__ A, const float* __restrict__ W1,
    const float* __restrict__ b1, const float* __restrict__ g,
    const float* __restrict__ bb, float* __restrict__ H)
{
  int row = blockIdx.x, j = threadIdx.x;
  __shared__ float As[K];
  for (int i = j; i < K; i += 256) As[i] = A[row * K + i];
  __syncthreads();

  float a0 = 0.f, a1 = 0.f, a2 = 0.f, a3 = 0.f;
  const float* __restrict__ Wp = W1 + j;
#pragma unroll 2
  for (int c = 0; c < K; c += 8) {
    float w0 = Wp[(size_t)(c + 0) * 256];
    float w1 = Wp[(size_t)(c + 1) * 256];
    float w2 = Wp[(size_t)(c + 2) * 256];
    float w3 = Wp[(size_t)(c + 3) * 256];
    float w4 = Wp[(size_t)(c + 4) * 256];
    float w5 = Wp[(size_t)(c + 5) * 256];
    float w6 = Wp[(size_t)(c + 6) * 256];
    float w7 = Wp[(size_t)(c + 7) * 256];
    a0 += As[c + 0] * w0 + As[c + 4] * w4;
    a1 += As[c + 1] * w1 + As[c + 5] * w5;
    a2 += As[c + 2] * w2 + As[c + 6] * w6;
    a3 += As[c + 3] * w3 + As[c + 7] * w7;
  }
  float acc = ((a0 + a1) + (a2 + a3)) + b1[j];

  __shared__ float rs[256], rs2[256];
  rs[j] = acc; rs2[j] = acc * acc;
  __syncthreads();
  for (int st = 128; st > 0; st >>= 1) {
    if (j < st) { rs[j] += rs[j + st]; rs2[j] += rs2[j + st]; }
    __syncthreads();
  }
  float mu  = rs[0] * (1.f / 256.f);
  float var = rs2[0] * (1.f / 256.f) - mu * mu;
  float y = (acc - mu) * rsqrtf(var + EPS_C) * g[j] + bb[j];
  H[row * 256 + j] = fmaxf(y, 0.f);
}

// ---------- Vs[c][n*64+l] = emb[l][n*64+60+c], c=0..3 ----------
__global__ __launch_bounds__(256) void emb_sel(
    const float* __restrict__ Hs, const float* __restrict__ Ht,
    const float* __restrict__ sW2, const float* __restrict__ sb2,
    const float* __restrict__ tW2, const float* __restrict__ tb2,
    float* __restrict__ Vs)
{
  int n = blockIdx.x, tid = threadIdx.x;
  int l = tid >> 2, c = tid & 3;
  __shared__ float wS[256][4], wT[256][4];
  {
    size_t base = (size_t)tid * 65536 + (size_t)n * 64 + 60;
    float4 a = *(const float4*)&sW2[base];
    float4 t4 = *(const float4*)&tW2[base];
    wS[tid][0] = a.x;  wS[tid][1] = a.y;  wS[tid][2] = a.z;  wS[tid][3] = a.w;
    wT[tid][0] = t4.x; wT[tid][1] = t4.y; wT[tid][2] = t4.z; wT[tid][3] = t4.w;
  }
  __syncthreads();
  const float* __restrict__ hs = Hs + l * 256;
  const float* __restrict__ ht = Ht + l * 256;
  float acc = 0.f;
  for (int k = 0; k < 256; k += 8) {
#pragma unroll
    for (int u = 0; u < 8; ++u)
      acc += hs[k + u] * wS[k + u][c] + ht[k + u] * wT[k + u][c];
  }
  int jj = n * 64 + 60 + c;
  Vs[(size_t)c * 65536 + (size_t)n * 64 + l] = acc + sb2[jj] + tb2[jj];
}

// ---------- VsT[c][l][n] = Vs[c][n][l] ----------
__global__ __launch_bounds__(256) void vst_k(
    const float* __restrict__ Vs, float* __restrict__ VsT)
{
  int c = blockIdx.x >> 4, nb = blockIdx.x & 15;
  int n0 = nb << 6, tid = threadIdx.x;
  __shared__ float Tl[64][65];
#pragma unroll
  for (int i = 0; i < 4; ++i) {
    int flat = i * 1024 + tid * 4;
    int rr = flat >> 6, cc = flat & 63;
    float4 v = *(const float4*)&Vs[(size_t)c * 65536 + (size_t)(n0 + rr) * 64 + cc];
    Tl[rr][cc] = v.x; Tl[rr][cc+1] = v.y; Tl[rr][cc+2] = v.z; Tl[rr][cc+3] = v.w;
  }
  __syncthreads();
#pragma unroll
  for (int i = 0; i < 4; ++i) {
    int flat = i * 1024 + tid * 4;
    int rr = flat >> 6, cc = flat & 63;   // rr = l row, cc = n-local
    float4 st = { Tl[cc][rr], Tl[cc+1][rr], Tl[cc+2][rr], Tl[cc+3][rr] };
    *(float4*)&VsT[(size_t)c * 65536 + (size_t)rr * 1024 + n0 + cc] = st;
  }
}

// ---------- VaBt[c][l][n] = (Vs[c] @ B)^T ----------
__global__ __launch_bounds__(256) void vab_k(
    const float* __restrict__ Vs, const float* __restrict__ Bmat,
    float* __restrict__ VaBt)
{
  int c = blockIdx.x >> 4, nb = blockIdx.x & 15;
  int n0 = nb << 6, tid = threadIdx.x;
  int rg = tid >> 4, cg = tid & 15;
  __shared__ float Va[64][65], Bs[64][65];
#pragma unroll
  for (int i = 0; i < 4; ++i) {
    int flat = i * 1024 + tid * 4;
    int rr = flat >> 6, cc = flat & 63;
    float4 v = *(const float4*)&Vs[(size_t)c * 65536 + (size_t)(n0 + rr) * 64 + cc];
    Va[rr][cc] = v.x; Va[rr][cc+1] = v.y; Va[rr][cc+2] = v.z; Va[rr][cc+3] = v.w;
    float4 w = *(const float4*)&Bmat[flat];
    Bs[rr][cc] = w.x; Bs[rr][cc+1] = w.y; Bs[rr][cc+2] = w.z; Bs[rr][cc+3] = w.w;
  }
  __syncthreads();
  float acc[4][4];
#pragma unroll
  for (int i = 0; i < 4; ++i)
#pragma unroll
    for (int j = 0; j < 4; ++j) acc[i][j] = 0.f;
#pragma unroll 4
  for (int l = 0; l < 64; ++l) {
    float av[4], bv[4];
#pragma unroll
    for (int i = 0; i < 4; ++i) av[i] = Va[rg * 4 + i][l];
#pragma unroll
    for (int j = 0; j < 4; ++j) bv[j] = Bs[l][cg * 4 + j];
#pragma unroll
    for (int i = 0; i < 4; ++i)
#pragma unroll
      for (int j = 0; j < 4; ++j) acc[i][j] += av[i] * bv[j];
  }
  // acc[i][j] = VaB[n0+rg*4+i][cg*4+j] -> VaBt[c][l=cg*4+j][n0+rg*4+i]
#pragma unroll
  for (int j = 0; j < 4; ++j) {
    float4 st = { acc[0][j], acc[1][j], acc[2][j], acc[3][j] };
    *(float4*)&VaBt[(size_t)c * 65536 + (size_t)(cg * 4 + j) * 1024 + n0 + rg * 4] = st;
  }
}

// ---------- split-K skinny GEMM partials; MODE 1 gathers from observation ----------
template<int MODE>
__global__ __launch_bounds__(256) void skinny_part2(
    const float* __restrict__ A, const float* __restrict__ W,
    float* __restrict__ part, int K, int N)
{
  int jblocks = N >> 8;
  int jb = blockIdx.x % jblocks;
  int kc = blockIdx.x / jblocks;
  int k0 = kc << 6;
  int tid = threadIdx.x;
  __shared__ float ARs[4][64];
  {
    int c = tid >> 6, i = tid & 63;
    int k = k0 + i;
    float v;
    if (MODE == 0) v = A[c * K + k];
    else { int n = k >> 2, df = k & 3; v = A[n * 256 + df * 64 + 60 + c]; }
    ARs[c][i] = v;
  }
  __syncthreads();
  int j = (jb << 8) + tid;
  float acc0 = 0.f, acc1 = 0.f, acc2 = 0.f, acc3 = 0.f;
#pragma unroll
  for (int kk = 0; kk < 64; kk += 16) {
    float w[16];
#pragma unroll
    for (int u = 0; u < 16; ++u) w[u] = W[(size_t)(k0 + kk + u) * N + j];
#pragma unroll
    for (int u = 0; u < 16; ++u) {
      acc0 += ARs[0][kk + u] * w[u];
      acc1 += ARs[1][kk + u] * w[u];
      acc2 += ARs[2][kk + u] * w[u];
      acc3 += ARs[3][kk + u] * w[u];
    }
  }
  part[(size_t)(kc * 4 + 0) * N + j] = acc0;
  part[(size_t)(kc * 4 + 1) * N + j] = acc1;
  part[(size_t)(kc * 4 + 2) * N + j] = acc2;
  part[(size_t)(kc * 4 + 3) * N + j] = acc3;
}

// ---------- out[c][j] = relu(LN(sum_parts + bias)) ----------
template<int N_, int PARTS>
__global__ __launch_bounds__(256) void reduce_ln_relu(
    const float* __restrict__ part, const float* __restrict__ bias,
    const float* __restrict__ g, const float* __restrict__ bb,
    float* __restrict__ out)
{
  constexpr int PER = N_ >> 8;
  int c = blockIdx.x, tid = threadIdx.x;
  float x[PER];
  float s = 0.f, s2 = 0.f;
#pragma unroll
  for (int i = 0; i < PER; ++i) {
    int j = (i << 8) + tid;
    float v = bias[j];
#pragma unroll 8
    for (int p = 0; p < PARTS; ++p) v += part[(size_t)(p * 4 + c) * N_ + j];
    x[i] = v; s += v; s2 += v * v;
  }
  __shared__ float rs[256], rs2[256];
  rs[tid] = s; rs2[tid] = s2;
  __syncthreads();
  for (int st = 128; st > 0; st >>= 1) {
    if (tid < st) { rs[tid] += rs[tid + st]; rs2[tid] += rs2[tid + st]; }
    __syncthreads();
  }
  float mu  = rs[0] / (float)N_;
  float var = rs2[0] / (float)N_ - mu * mu;
  float inv = rsqrtf(var + EPS_C);
#pragma unroll
  for (int i = 0; i < PER; ++i) {
    int j = (i << 8) + tid;
    out[c * N_ + j] = fmaxf((x[i] - mu) * inv * g[j] + bb[j], 0.f);
  }
}

// ---------- Xr[c][j] = sum_k h2[c][k]*fW3[k][j] + fb3[j] ; 2-way k-split ----------
__global__ __launch_bounds__(256) void big_w3(
    const float* __restrict__ h2, const float* __restrict__ fW3,
    const float* __restrict__ fb3, float* __restrict__ Xr)
{
  int tid = threadIdx.x;
  __shared__ float h2s[2048];
  __shared__ float sm[4][128];
  for (int i = tid; i < 2048; i += 256) h2s[i] = h2[i];
  int col = tid & 127, ks = tid >> 7;
  int j = blockIdx.x * 128 + col;
  int kbase = ks << 8;
  __syncthreads();
  float acc0 = 0.f, acc1 = 0.f, acc2 = 0.f, acc3 = 0.f;
  for (int k0 = 0; k0 < 256; k0 += 16) {
    float w[16];
#pragma unroll
    for (int u = 0; u < 16; ++u) w[u] = fW3[(size_t)(kbase + k0 + u) * 65536 + j];
#pragma unroll
    for (int u = 0; u < 16; ++u) {
      int k = kbase + k0 + u;
      acc0 += h2s[k]        * w[u];
      acc1 += h2s[512 + k]  * w[u];
      acc2 += h2s[1024 + k] * w[u];
      acc3 += h2s[1536 + k] * w[u];
    }
  }
  if (ks) { sm[0][col] = acc0; sm[1][col] = acc1; sm[2][col] = acc2; sm[3][col] = acc3; }
  __syncthreads();
  if (!ks) {
    float b = fb3[j];
    Xr[j]            = acc0 + sm[0][col] + b;
    Xr[65536 + j]    = acc1 + sm[1][col] + b;
    Xr[131072 + j]   = acc2 + sm[2][col] + b;
    Xr[196608 + j]   = acc3 + sm[3][col] + b;
  }
}

// ---------- split-flash attention partial, transposed LDS (b128 reads) ----------
__global__ __launch_bounds__(256) void attn_partial(
    const float* __restrict__ VaBt, const float* __restrict__ VsT,
    const float* __restrict__ Xbase, float* __restrict__ Pl,
    float* __restrict__ ml, Pairs pr, int slotBase)
{
  int pi  = blockIdx.x >> 7;
  int rem = blockIdx.x & 127;
  int nb  = rem >> 3;
  int s   = rem & 7;
  int n0  = nb << 6;
  int tid = threadIdx.x;
  int rg = tid >> 4, cg = tid & 15;
  int rg4 = rg * 4, cg4 = cg * 4;
  int a = pr.a[pi], b = pr.b[pi], t = pr.t[pi];

  __shared__ __align__(16) float VaT[64][68];  // [p][n-local]
  __shared__ __align__(16) float VbT[64][68];  // [p][q-local]
  __shared__ __align__(16) float Xs[64][68];   // [q-local][f]
  __shared__ float St[64][65];                 // [n-local][q-local]
  __shared__ float rowm[64], rowl[64], rowsc[64];

#pragma unroll
  for (int i = 0; i < 4; ++i) {
    int flat = i * 1024 + tid * 4;
    int p = flat >> 6, nn = flat & 63;
    float4 v = *(const float4*)&VaBt[(size_t)a * 65536 + (size_t)p * 1024 + n0 + nn];
    *(float4*)&VaT[p][nn] = v;
  }
  if (tid < 64) { rowm[tid] = -1e30f; rowl[tid] = 0.f; }
  __syncthreads();

  float P[4][4];
#pragma unroll
  for (int i = 0; i < 4; ++i)
#pragma unroll
    for (int j = 0; j < 4; ++j) P[i][j] = 0.f;

  for (int ti = 0; ti < 2; ++ti) {
    int q0 = (s << 7) + (ti << 6);
    if (ti) __syncthreads();
#pragma unroll
    for (int i = 0; i < 4; ++i) {
      int flat = i * 1024 + tid * 4;
      int p = flat >> 6, qq = flat & 63;
      float4 v = *(const float4*)&VsT[(size_t)b * 65536 + (size_t)p * 1024 + q0 + qq];
      *(float4*)&VbT[p][qq] = v;
      float4 x = *(const float4*)&Xbase[(size_t)t * 65536 + (size_t)(q0 + p) * 64 + qq];
      *(float4*)&Xs[p][qq] = x;
    }
    __syncthreads();
    // S tile + threshold
    float sa[4][4];
#pragma unroll
    for (int i = 0; i < 4; ++i)
#pragma unroll
      for (int j = 0; j < 4; ++j) sa[i][j] = 0.f;
#pragma unroll 4
    for (int p = 0; p < 64; ++p) {
      float av[4], bv[4];
      *(float4*)av = *(const float4*)&VaT[p][rg4];
      *(float4*)bv = *(const float4*)&VbT[p][cg4];
#pragma unroll
      for (int i = 0; i < 4; ++i)
#pragma unroll
        for (int j = 0; j < 4; ++j) sa[i][j] += av[i] * bv[j];
    }
#pragma unroll
    for (int i = 0; i < 4; ++i)
#pragma unroll
      for (int j = 0; j < 4; ++j) {
        float sv = sa[i][j];
        St[rg4 + i][cg4 + j] = (sv >= DELTA_C) ? sv : 0.f;
      }
    __syncthreads();
    // wave-parallel online softmax: 4 lanes per row
    {
      int r = tid >> 2, sub = tid & 3;
      float tm = -1e30f;
#pragma unroll
      for (int jj = 0; jj < 16; ++jj) tm = fmaxf(tm, St[r][sub * 16 + jj]);
      tm = fmaxf(tm, __shfl_xor(tm, 1));
      tm = fmaxf(tm, __shfl_xor(tm, 2));
      float mold = rowm[r];
      float mnew = fmaxf(mold, tm);
      float ssum = 0.f;
#pragma unroll
      for (int jj = 0; jj < 16; ++jj) {
        float e = __expf(St[r][sub * 16 + jj] - mnew);
        St[r][sub * 16 + jj] = e;
        ssum += e;
      }
      ssum += __shfl_xor(ssum, 1);
      ssum += __shfl_xor(ssum, 2);
      if (sub == 0) {
        float sc = __expf(mold - mnew);
        rowsc[r] = sc;
        rowl[r] = rowl[r] * sc + ssum;
        rowm[r] = mnew;
      }
    }
    __syncthreads();
    // rescale + PV
    float scv[4];
#pragma unroll
    for (int i = 0; i < 4; ++i) scv[i] = rowsc[rg4 + i];
#pragma unroll
    for (int i = 0; i < 4; ++i)
#pragma unroll
      for (int j = 0; j < 4; ++j) P[i][j] *= scv[i];
#pragma unroll 4
    for (int q = 0; q < 64; ++q) {
      float ev[4], xv[4];
#pragma unroll
      for (int i = 0; i < 4; ++i) ev[i] = St[rg4 + i][q];
      *(float4*)xv = *(const float4*)&Xs[q][cg4];
#pragma unroll
      for (int i = 0; i < 4; ++i)
#pragma unroll
        for (int j = 0; j < 4; ++j) P[i][j] += ev[i] * xv[j];
    }
  }
  size_t base = (size_t)((slotBase + pi) * 16 + nb) * NS + s;
  float* pp = Pl + base * 4096;
#pragma unroll
  for (int i = 0; i < 4; ++i) {
    float4 st = { P[i][0], P[i][1], P[i][2], P[i][3] };
    *(float4*)&pp[(size_t)(rg4 + i) * 64 + cg4] = st;
  }
  if (tid < 64) {
    float* mlp = ml + base * 128;
    mlp[tid]      = rowm[tid];
    mlp[64 + tid] = rowl[tid];
  }
}

// ---------- per-instance merge + W GEMM -> Gp ----------
__global__ __launch_bounds__(256) void merge_partial(
    const float* __restrict__ Pl, const float* __restrict__ ml,
    const float* __restrict__ Wf, const float* __restrict__ Wb,
    int slotBase, float* __restrict__ Gp)
{
  int mm = blockIdx.x / 48;
  int rem = blockIdx.x % 48;
  int nb = rem / 3, inst = rem % 3;
  int n0 = nb << 6;
  int tid = threadIdx.x;
  int rg = tid >> 4, cg = tid & 15;
  int rg4 = rg * 4, cg4 = cg * 4;
  int r = tid >> 2, sub = tid & 3;

  __shared__ __align__(16) float PtT[64][68];  // [f][n]
  __shared__ __align__(16) float Wt[64][68];   // [f][out]

  int slot = slotBase + mm * 3 + inst;
  size_t base = (size_t)(slot * 16 + nb) * NS;
  const float* mlp = ml + base * 128;
  float mg = -1e30f;
#pragma unroll
  for (int s2 = 0; s2 < NS; ++s2) mg = fmaxf(mg, mlp[s2 * 128 + r]);
  float acc[16];
#pragma unroll
  for (int u = 0; u < 16; ++u) acc[u] = 0.f;
  float lg = 0.f;
#pragma unroll
  for (int s2 = 0; s2 < NS; ++s2) {
    float f = __expf(mlp[s2 * 128 + r] - mg);
    lg += f * mlp[s2 * 128 + 64 + r];
    const float4* ps = (const float4*)(Pl + (base + s2) * 4096 + r * 64 + sub * 16);
#pragma unroll
    for (int u = 0; u < 4; ++u) {
      float4 v = ps[u];
      acc[u*4+0] += f * v.x; acc[u*4+1] += f * v.y;
      acc[u*4+2] += f * v.z; acc[u*4+3] += f * v.w;
    }
  }
  float inv = 1.f / lg;
#pragma unroll
  for (int u = 0; u < 16; ++u) PtT[sub * 16 + u][r] = acc[u] * inv;
  for (int i = tid; i < 4096; i += 256) {
    int rr = i >> 6, cc = i & 63;
    float w;
    if (inst == 0)      w = Wf[i] + Wb[i];
    else if (inst == 1) w = Wf[4096 + i];
    else                w = Wb[4096 + i];
    Wt[rr][cc] = w;
  }
  __syncthreads();
  float g2[4][4];
#pragma unroll
  for (int i = 0; i < 4; ++i)
#pragma unroll
    for (int j = 0; j < 4; ++j) g2[i][j] = 0.f;
#pragma unroll 4
  for (int ff = 0; ff < 64; ++ff) {
    float p[4], w[4];
    *(float4*)p = *(const float4*)&PtT[ff][rg4];
    *(float4*)w = *(const float4*)&Wt[ff][cg4];
#pragma unroll
    for (int i = 0; i < 4; ++i)
#pragma unroll
      for (int j = 0; j < 4; ++j) g2[i][j] += p[i] * w[j];
  }
#pragma unroll
  for (int i = 0; i < 4; ++i) {
    float4 st = { g2[i][0], g2[i][1], g2[i][2], g2[i][3] };
    *(float4*)&Gp[(size_t)(mm * 3 + inst) * 65536 + (size_t)(n0 + rg4 + i) * 64 + cg4] = st;
  }
}

// ---------- Z = tanh(G0+b) + tanh(G1+G2+b) ----------
__global__ __launch_bounds__(256) void finalize_z(
    const float* __restrict__ Gp, const float* __restrict__ bconv,
    float* __restrict__ dst0, float* __restrict__ dst1, float* __restrict__ extra1)
{
  int mm = blockIdx.x >> 4;
  int nb = blockIdx.x & 15;
  int tid = threadIdx.x;
  size_t tileOff = (size_t)(nb << 6) * 64;
  const float* g0 = Gp + (size_t)(mm * 3 + 0) * 65536 + tileOff;
  const float* g1 = Gp + (size_t)(mm * 3 + 1) * 65536 + tileOff;
  const float* g2 = Gp + (size_t)(mm * 3 + 2) * 65536 + tileOff;
  float* dst = (mm == 0) ? dst0 : dst1;
  for (int i = tid * 4; i < 4096; i += 1024) {
    float4 a = *(const float4*)&g0[i];
    float4 b = *(const float4*)&g1[i];
    float4 c = *(const float4*)&g2[i];
    int col = i & 63;
    float4 z;
    z.x = tanhf(a.x + bconv[col+0]) + tanhf(b.x + c.x + bconv[col+0]);
    z.y = tanhf(a.y + bconv[col+1]) + tanhf(b.y + c.y + bconv[col+1]);
    z.z = tanhf(a.z + bconv[col+2]) + tanhf(b.z + c.z + bconv[col+2]);
    z.w = tanhf(a.w + bconv[col+3]) + tanhf(b.w + c.w + bconv[col+3]);
    *(float4*)&dst[tileOff + i] = z;
    if (mm == 1 && extra1) *(float4*)&extra1[tileOff + i] = z;
  }
}

extern "C" void kernel_launch(void* const* d_in, const int* in_sizes, int n_in,
                              void* d_out, int out_size, void* d_ws, size_t ws_size,
                              hipStream_t stream)
{
  const float* observation   = (const float*)d_in[0];
  const float* time_features = (const float*)d_in[1];
  const float* layer_initial = (const float*)d_in[2];
  const float* sW1   = (const float*)d_in[3];
  const float* sb1   = (const float*)d_in[4];
  const float* s_ln_g = (const float*)d_in[5];
  const float* s_ln_b = (const float*)d_in[6];
  const float* sW2   = (const float*)d_in[7];
  const float* sb2   = (const float*)d_in[8];
  const float* tW1   = (const float*)d_in[9];
  const float* tb1   = (const float*)d_in[10];
  const float* t_ln_g = (const float*)d_in[11];
  const float* t_ln_b = (const float*)d_in[12];
  const float* tW2   = (const float*)d_in[13];
  const float* tb2   = (const float*)d_in[14];
  const float* Bmat  = (const float*)d_in[15];
  const float* fW1   = (const float*)d_in[16];
  const float* fb1   = (const float*)d_in[17];
  const float* f1g   = (const float*)d_in[18];
  const float* f1b   = (const float*)d_in[19];
  const float* fW2   = (const float*)d_in[20];
  const float* fb2   = (const float*)d_in[21];
  const float* f2g   = (const float*)d_in[22];
  const float* f2b   = (const float*)d_in[23];
  const float* fW3   = (const float*)d_in[24];
  const float* fb3   = (const float*)d_in[25];
  const float* Wf    = (const float*)d_in[26];
  const float* Wb    = (const float*)d_in[27];
  const float* bconv = (const float*)d_in[28];
  float* out = (float*)d_out;

  float* ws    = (float*)d_ws;
  float* Hs    = ws;                  // 16384
  float* Ht    = Hs    + 16384;       // 16384
  float* Vs    = Ht    + 16384;       // 262144
  float* VsT   = Vs    + 262144;      // 262144
  float* VaBt  = VsT   + 262144;      // 262144
  float* part  = VaBt  + 262144;      // 262144
  float* h1    = part  + 262144;      // 4096
  float* h2    = h1    + 4096;        // 2048
  float* Xr    = h2    + 2048;        // 262144
  float* Pl    = Xr    + 262144;      // 4,718,592
  float* ml    = Pl    + 4718592;     // 147,456
  float* Z1    = ml    + 147456;      // 131072
  float* Gp    = Z1    + 131072;      // 393216 (6 x 65536)

  head_mlp_t<1024><<<64, 256, 0, stream>>>(layer_initial, sW1, sb1, s_ln_g, s_ln_b, Hs);
  head_mlp_t<8><<<64, 256, 0, stream>>>(time_features, tW1, tb1, t_ln_g, t_ln_b, Ht);
  emb_sel<<<1024, 256, 0, stream>>>(Hs, Ht, sW2, sb2, tW2, tb2, Vs);
  vst_k<<<64, 256, 0, stream>>>(Vs, VsT);
  vab_k<<<64, 256, 0, stream>>>(Vs, Bmat, VaBt);

  skinny_part2<1><<<256, 256, 0, stream>>>(observation, fW1, part, 4096, 1024);  // 64 kc x 4 jb
  reduce_ln_relu<1024, 64><<<4, 256, 0, stream>>>(part, fb1, f1g, f1b, h1);
  skinny_part2<0><<<32, 256, 0, stream>>>(h1, fW2, part, 1024, 512);             // 16 kc x 2 jb
  reduce_ln_relu<512, 16><<<4, 256, 0, stream>>>(part, fb2, f2g, f2b, h2);
  big_w3<<<512, 256, 0, stream>>>(h2, fW3, fb3, Xr);

  // layer-1, m=30 (cols 60/61, X rows 0/1) and m=31 (cols 62/63, X rows 2/3)
  Pairs pA;
  pA.a[0]=1; pA.b[0]=1; pA.t[0]=1;   // k=0, m=30: A(61,61) @ X[61]
  pA.a[1]=0; pA.b[1]=1; pA.t[1]=0;   // k=1, m=30: A(60,61) @ X[60]
  pA.a[2]=1; pA.b[2]=0; pA.t[2]=0;   // k=1, m=30: A(61,60) @ X[60]
  pA.a[3]=3; pA.b[3]=3; pA.t[3]=3;   // k=0, m=31: A(63,63) @ X[63]
  pA.a[4]=2; pA.b[4]=3; pA.t[4]=2;   // k=1, m=31: A(62,63) @ X[62]
  pA.a[5]=3; pA.b[5]=2; pA.t[5]=2;   // k=1, m=31: A(63,62) @ X[62]
  attn_partial<<<6 * 16 * NS, 256, 0, stream>>>(VaBt, VsT, Xr, Pl, ml, pA, 0);
  merge_partial<<<96, 256, 0, stream>>>(Pl, ml, Wf, Wb, 0, Gp);
  finalize_z<<<32, 256, 0, stream>>>(Gp, bconv, Z1, Z1 + 65536, out);

  // layer-2, m=15: cols 62(=2)/60(=0), X = Z1 rows {0: m30, 1: m31}
  Pairs pB;
  pB.a[0]=2; pB.b[0]=2; pB.t[0]=1;   // k=0: A(62,62) @ X1[31]
  pB.a[1]=0; pB.b[1]=2; pB.t[1]=0;   // k=1: A(60,62) @ X1[30]
  pB.a[2]=2; pB.b[2]=0; pB.t[2]=0;   // k=1: A(62,60) @ X1[30]
  pB.a[3]=pB.a[4]=pB.a[5]=0; pB.b[3]=pB.b[4]=pB.b[5]=0; pB.t[3]=pB.t[4]=pB.t[5]=0;
  attn_partial<<<3 * 16 * NS, 256, 0, stream>>>(VaBt, VsT, Z1, Pl, ml, pB, 6);
  merge_partial<<<48, 256, 0, stream>>>(Pl, ml, Wf, Wb, 6, Gp);
  finalize_z<<<16, 256, 0, stream>>>(Gp, bconv, out + 65536, nullptr, nullptr);
}